// Round 14
// baseline (265.699 us; speedup 1.0000x reference)
//
#include <hip/hip_runtime.h>
#include <hip/hip_bf16.h>
#include <math.h>

#define NND 20000
#define NED 320000
#define NB 4
#define NFEAT 8
#define ADF 8
#define DD 128
#define MROWS (NB * NND)
#define NEGINF -1000000000.0f
#define NCH 16
#define EPC (NED / NCH)     // 20000 edges per chunk
#define NPART 8
#define PSZ (NND / NPART)   // 2500 nodes per part
#define DEGB (NB * NPART * NCH)  // 512 blocks
#define NSEG 32
#define SEGSZ (NND / NSEG)  // 625 nodes per scan segment

typedef __attribute__((ext_vector_type(8))) short short8;
typedef __attribute__((ext_vector_type(4))) float f32x4;

__device__ __forceinline__ unsigned ftrans(float f) {
    unsigned u = __float_as_uint(f);
    return (u & 0x80000000u) ? ~u : (u | 0x80000000u);
}
__device__ __forceinline__ float finv(unsigned t) {
    unsigned u = (t & 0x80000000u) ? (t & 0x7fffffffu) : ~t;
    return __uint_as_float(u);
}
__device__ __forceinline__ unsigned short f2bf(float f) {  // RNE, finite inputs
    unsigned u = __float_as_uint(f);
    unsigned r = u + 0x7fffu + ((u >> 16) & 1u);
    return (unsigned short)(r >> 16);
}
__device__ __forceinline__ float bf2f(unsigned short b) {
    return __uint_as_float(((unsigned)b) << 16);
}
__device__ __forceinline__ void unpack8(uint4 v, float* f) {
    f[0] = __uint_as_float(v.x << 16); f[1] = __uint_as_float(v.x & 0xffff0000u);
    f[2] = __uint_as_float(v.y << 16); f[3] = __uint_as_float(v.y & 0xffff0000u);
    f[4] = __uint_as_float(v.z << 16); f[5] = __uint_as_float(v.z & 0xffff0000u);
    f[6] = __uint_as_float(v.w << 16); f[7] = __uint_as_float(v.w & 0xffff0000u);
}

// ---------------- init scratch + mask dtype flag ----------------
__global__ __launch_bounds__(256) void k_init(float* stats, unsigned* mtrans, float* S, float* ctx,
                                              const unsigned char* __restrict__ m, int* flag) {
    if (blockIdx.x == 2) {
        __shared__ int any;
        if (threadIdx.x == 0) any = 0;
        __syncthreads();
        int found = 0;
        for (int p = threadIdx.x; p < 4096; p += 256)
            if ((p & 3) && m[p]) found = 1;
        if (found) atomicOr(&any, 1);
        __syncthreads();
        if (threadIdx.x == 0) *flag = any;
        return;
    }
    int i = blockIdx.x * 256 + threadIdx.x;
    if (i < 16) stats[i] = 0.f;
    if (i < NB) { mtrans[i] = 0u; S[i] = 0.f; }
    if (i < NB * DD) ctx[i] = 0.f;
}

// ---------------- fused setup: deg-partials(LDS hist, 512 blk) + stats + maskc + prep + ad ----------------
__global__ __launch_bounds__(256) void k_setup(const int* __restrict__ links, int* __restrict__ dp,
                                               const float* __restrict__ nodes, float* stats,
                                               const void* __restrict__ m, const int* __restrict__ flag,
                                               int* __restrict__ mc,
                                               const float* __restrict__ Wm1, const float* __restrict__ Ws1,
                                               const float* __restrict__ Wm2, const float* __restrict__ Ws2,
                                               const float* __restrict__ Wp,
                                               unsigned short* __restrict__ B1t, unsigned short* __restrict__ B2t,
                                               unsigned short* __restrict__ Bpt,
                                               const float* __restrict__ ad, const float* __restrict__ Wad,
                                               const float* __restrict__ bad, float* __restrict__ av,
                                               unsigned short* __restrict__ av_bf) {
    __shared__ int hist[PSZ];  // 10 KiB
    int bid = blockIdx.x, tid = threadIdx.x;
    if (bid < DEGB) {
        int part = bid & 7;
        int b = (bid >> 3) & 3;
        int c = bid >> 5;
        const int lo = part * PSZ;
        for (int i = tid; i < PSZ; i += 256) hist[i] = 0;
        __syncthreads();
        const int4* dstp4 = (const int4*)(links + b * 2 * NED + NED + c * EPC);
        for (int q = tid; q < EPC / 4; q += 256) {
            int4 d = dstp4[q];
            if (d.x >= lo && d.x < lo + PSZ) atomicAdd(&hist[d.x - lo], 1);
            if (d.y >= lo && d.y < lo + PSZ) atomicAdd(&hist[d.y - lo], 1);
            if (d.z >= lo && d.z < lo + PSZ) atomicAdd(&hist[d.z - lo], 1);
            if (d.w >= lo && d.w < lo + PSZ) atomicAdd(&hist[d.w - lo], 1);
        }
        __syncthreads();
        int* out = dp + (size_t)(b * NCH + c) * NND + lo;
        for (int i = tid; i < PSZ; i += 256) out[i] = hist[i];
        return;
    }
    if (bid < DEGB + 256) {
        int gid = (bid - DEGB) * 256 + tid;
        float s[8] = {0.f,0.f,0.f,0.f,0.f,0.f,0.f,0.f};
        float q[8] = {0.f,0.f,0.f,0.f,0.f,0.f,0.f,0.f};
        for (int r = gid; r < NB * NND; r += 256 * 256) {
            const float* p = nodes + (size_t)r * NFEAT;
#pragma unroll
            for (int k = 0; k < 8; ++k) { float v = p[k]; s[k] += v; q[k] += v * v; }
        }
#pragma unroll
        for (int k = 0; k < 8; ++k) {
            for (int off = 32; off; off >>= 1) {
                s[k] += __shfl_xor(s[k], off, 64);
                q[k] += __shfl_xor(q[k], off, 64);
            }
        }
        __shared__ float ls[4][16];
        int w = tid >> 6, lane = tid & 63;
        if (lane == 0) {
#pragma unroll
            for (int k = 0; k < 8; ++k) { ls[w][k] = s[k]; ls[w][8 + k] = q[k]; }
        }
        __syncthreads();
        if (tid < 16) {
            float t = ls[0][tid] + ls[1][tid] + ls[2][tid] + ls[3][tid];
            atomicAdd(stats + tid, t);
        }
        return;
    }
    if (bid < DEGB + 256 + 313) {
        int g = (bid - DEGB - 256) * 256 + tid;
        if (g < NB * NND) {
            int f = *flag;
            mc[g] = f ? (int)((const unsigned char*)m)[g] : ((const int*)m)[g];
        }
        return;
    }
    if (bid < DEGB + 256 + 313 + 3) {
        int mtx = bid - (DEGB + 256 + 313);
        const float* S0 = (mtx == 0) ? Wm1 : ((mtx == 1) ? Wm2 : Wp);
        const float* S1 = (mtx == 0) ? Ws1 : ((mtx == 1) ? Ws2 : (Wp + 128 * DD));
        unsigned short* D = (mtx == 0) ? B1t : ((mtx == 1) ? B2t : Bpt);
        for (int idx = tid; idx < 128 * 32; idx += 256) {
            int n = idx >> 5;
            int mm = idx & 31;
            short8 pk;
#pragma unroll
            for (int j = 0; j < 8; ++j) {
                int k = mm * 8 + j;
                float v = (k < 128) ? S0[k * DD + n] : S1[(k - 128) * DD + n];
                pk[j] = (short)f2bf(v);
            }
            int mst = mm ^ (n & 7);
            *(short8*)(D + n * 256 + mst * 8) = pk;
        }
        return;
    }
    // ad head (1 block)
    __shared__ float sn[NB * ADF];
    if (tid < ADF) {
        float mm = 0.f;
        for (int b = 0; b < NB; ++b) mm += ad[b * ADF + tid];
        mm *= 0.25f;
        float v = 0.f;
        for (int b = 0; b < NB; ++b) { float d = ad[b * ADF + tid] - mm; v += d * d; }
        v *= 0.25f;
        float r = 1.f / (sqrtf(v) + 1e-8f);
        for (int b = 0; b < NB; ++b) sn[b * ADF + tid] = (ad[b * ADF + tid] - mm) * r;
    }
    __syncthreads();
    for (int t = tid; t < NB * DD; t += 256) {
        int b = t >> 7, j = t & 127;
        float acc = bad[j];
#pragma unroll
        for (int k = 0; k < 8; ++k) acc += sn[b * ADF + k] * Wad[k * DD + j];
        float rl = fmaxf(acc, 0.f);
        av[t] = rl;
        av_bf[t] = f2bf(rl);
    }
}

// ---------------- h0 = relu(norm(nodes) @ W_in + b_in) -> bf16 (grid-stride, 8 cols/thread) ----------------
__global__ __launch_bounds__(256) void k_h0(const float* __restrict__ nodes, const float* __restrict__ stats,
                                            const float* __restrict__ Win, const float* __restrict__ bin,
                                            unsigned short* __restrict__ h) {
    __shared__ float sW[NFEAT * DD];
    __shared__ float sb[DD];
    __shared__ float sm[8], sr[8];
    int tid = threadIdx.x;
    for (int i = tid; i < NFEAT * DD; i += 256) sW[i] = Win[i];
    if (tid < DD) sb[tid] = bin[tid];
    if (tid < 8) {
        float inv_n = 1.f / (float)(NB * NND);
        float mean = stats[tid] * inv_n;
        float var = stats[8 + tid] * inv_n - mean * mean;
        var = fmaxf(var, 0.f);
        sm[tid] = mean;
        sr[tid] = 1.f / (sqrtf(var) + 1e-8f);
    }
    __syncthreads();
    for (int t = blockIdx.x * 256 + tid; t < NB * NND * 16; t += 2048 * 256) {
        int bn = t >> 4;
        int j0 = (t & 15) << 3;
        const float* p = nodes + (size_t)bn * NFEAT;
        float acc[8];
#pragma unroll
        for (int jj = 0; jj < 8; ++jj) acc[jj] = sb[j0 + jj];
#pragma unroll
        for (int k = 0; k < 8; ++k) {
            float x = (p[k] - sm[k]) * sr[k];
#pragma unroll
            for (int jj = 0; jj < 8; ++jj) acc[jj] += x * sW[k * DD + j0 + jj];
        }
        uint4 r;
        r.x = ((unsigned)f2bf(fmaxf(acc[1], 0.f)) << 16) | (unsigned)f2bf(fmaxf(acc[0], 0.f));
        r.y = ((unsigned)f2bf(fmaxf(acc[3], 0.f)) << 16) | (unsigned)f2bf(fmaxf(acc[2], 0.f));
        r.z = ((unsigned)f2bf(fmaxf(acc[5], 0.f)) << 16) | (unsigned)f2bf(fmaxf(acc[4], 0.f));
        r.w = ((unsigned)f2bf(fmaxf(acc[7], 0.f)) << 16) | (unsigned)f2bf(fmaxf(acc[6], 0.f));
        *(uint4*)(h + (size_t)bn * DD + j0) = r;
    }
}

// ---------------- 3-phase parallel scan ----------------
__global__ __launch_bounds__(1024) void k_scanA(const int* __restrict__ dp, int* __restrict__ offs,
                                                int* __restrict__ segsum) {
    int b = blockIdx.x >> 5, seg = blockIdx.x & 31;
    int tid = threadIdx.x, lane = tid & 63, wv = tid >> 6;
    __shared__ int wsum[16], wexcl[16];
    int i = seg * SEGSZ + tid;
    int v = 0;
    if (tid < SEGSZ) {
#pragma unroll
        for (int q = 0; q < NCH; ++q) v += dp[(size_t)(b * NCH + q) * NND + i];
    }
    int x = v;
#pragma unroll
    for (int d = 1; d < 64; d <<= 1) {
        int t = __shfl_up(x, d, 64);
        if (lane >= d) x += t;
    }
    if (lane == 63) wsum[wv] = x;
    __syncthreads();
    if (wv == 0) {
        int s = (lane < 16) ? wsum[lane] : 0;
#pragma unroll
        for (int d = 1; d < 16; d <<= 1) {
            int t = __shfl_up(s, d, 64);
            if (lane >= d) s += t;
        }
        if (lane < 16) wexcl[lane] = s - wsum[lane];
    }
    __syncthreads();
    int excl = wexcl[wv] + (x - v);
    if (tid < SEGSZ) offs[b * (NND + 1) + i] = excl;
    if (tid == SEGSZ - 1) segsum[blockIdx.x] = excl + v;
}

__global__ void k_scanB(int* __restrict__ segsum, int* __restrict__ offs) {
    int tid = threadIdx.x;
    if (tid < NB) {
        int run = 0;
        for (int s = 0; s < NSEG; ++s) {
            int t = segsum[tid * NSEG + s];
            segsum[tid * NSEG + s] = run;
            run += t;
        }
        offs[tid * (NND + 1) + NND] = run;
    }
}

__global__ __launch_bounds__(1024) void k_scanC(int* __restrict__ dp, int* __restrict__ offs,
                                                const int* __restrict__ segsum) {
    int b = blockIdx.x >> 5, seg = blockIdx.x & 31;
    int tid = threadIdx.x;
    if (tid >= SEGSZ) return;
    int i = seg * SEGSZ + tid;
    int excl = segsum[blockIdx.x] + offs[b * (NND + 1) + i];
    offs[b * (NND + 1) + i] = excl;
    int run = excl;
#pragma unroll
    for (int q = 0; q < NCH; ++q) {
        size_t a = (size_t)(b * NCH + q) * NND + i;
        int p = dp[a];
        dp[a] = run;
        run += p;
    }
}

// ---------------- CSR fill via LDS cursors (512 blocks, no global atomics, plain int4 reads) ----------------
__global__ __launch_bounds__(256) void k_fill(const int* __restrict__ links, const int* __restrict__ dp,
                                              int* __restrict__ csr) {
    __shared__ int cur[PSZ];  // 10 KiB
    int bid = blockIdx.x, tid = threadIdx.x;
    int part = bid & 7;
    int b = (bid >> 3) & 3;
    int c = bid >> 5;
    const int lo = part * PSZ;
    const int* cstart = dp + (size_t)(b * NCH + c) * NND + lo;
    for (int i = tid; i < PSZ; i += 256) cur[i] = cstart[i];
    __syncthreads();
    const int4* dstp4 = (const int4*)(links + b * 2 * NED + NED + c * EPC);
    const int* srcp = links + b * 2 * NED + c * EPC;
    int* cs = csr + (size_t)b * NED;
    for (int q = tid; q < EPC / 4; q += 256) {
        int4 d = dstp4[q];
        int e = q * 4;
        if (d.x >= lo && d.x < lo + PSZ) { int pos = atomicAdd(&cur[d.x - lo], 1); cs[pos] = srcp[e]; }
        if (d.y >= lo && d.y < lo + PSZ) { int pos = atomicAdd(&cur[d.y - lo], 1); cs[pos] = srcp[e + 1]; }
        if (d.z >= lo && d.z < lo + PSZ) { int pos = atomicAdd(&cur[d.z - lo], 1); cs[pos] = srcp[e + 2]; }
        if (d.w >= lo && d.w < lo + PSZ) { int pos = atomicAdd(&cur[d.w - lo], 1); cs[pos] = srcp[e + 3]; }
    }
}

// ---------------- agg[n] = sum_{src->n} h[src]  (wave/node + XCD-batch affinity, pipelined inner loop) ----------------
__global__ __launch_bounds__(256) void k_gather(const unsigned short* __restrict__ h, const int* __restrict__ offs,
                                                const int* __restrict__ csr, unsigned short* __restrict__ agg) {
    int bid = blockIdx.x;
    int xcd = bid & 7;
    int b = xcd >> 1;
    int sub = (bid >> 3) * 2 + (xcd & 1);       // [0, 5000) within batch
    int n = sub * 4 + (threadIdx.x >> 6);       // 4 waves -> 4 consecutive nodes
    int lane = threadIdx.x & 63;
    if (n >= NND) return;
    int wid = b * NND + n;
    int off0 = offs[b * (NND + 1) + n];
    int off1 = offs[b * (NND + 1) + n + 1];
    int g = lane >> 4, c = lane & 15;
    float acc[8] = {0.f,0.f,0.f,0.f,0.f,0.f,0.f,0.f};
    const uint4* hb = (const uint4*)(h + (size_t)b * NND * DD);
    const int* cs = csr + (size_t)b * NED;
    for (int base = off0; base < off1; base += 64) {
        int cnt = min(64, off1 - base);
        int idx = (lane < cnt) ? cs[base + lane] : 0;
        int full = cnt >> 2;   // iterations where all 4 lane-groups are valid
        if (full > 0) {
            // 2-stage pipeline: next iteration's shfl+load issued before current accumulate
            int srcn = __shfl(idx, g, 64);
            uint4 v = hb[srcn * 16 + c];
            for (int j = 1; j < full; ++j) {
                int srcn2 = __shfl(idx, j * 4 + g, 64);
                uint4 v2 = hb[srcn2 * 16 + c];
                float f[8];
                unpack8(v, f);
#pragma unroll
                for (int k = 0; k < 8; ++k) acc[k] += f[k];
                v = v2;
            }
            float f[8];
            unpack8(v, f);
#pragma unroll
            for (int k = 0; k < 8; ++k) acc[k] += f[k];
        }
        int q = full * 4 + g;   // tail (q <= 63 always)
        int srcn = __shfl(idx, q, 64);
        if (q < cnt) {
            uint4 v = hb[srcn * 16 + c];
            float f[8];
            unpack8(v, f);
#pragma unroll
            for (int k = 0; k < 8; ++k) acc[k] += f[k];
        }
    }
#pragma unroll
    for (int k = 0; k < 8; ++k) {
        acc[k] += __shfl_xor(acc[k], 16, 64);
        acc[k] += __shfl_xor(acc[k], 32, 64);
    }
    if (lane < 16) {
        uint4 r;
        r.x = ((unsigned)f2bf(acc[1]) << 16) | (unsigned)f2bf(acc[0]);
        r.y = ((unsigned)f2bf(acc[3]) << 16) | (unsigned)f2bf(acc[2]);
        r.z = ((unsigned)f2bf(acc[5]) << 16) | (unsigned)f2bf(acc[4]);
        r.w = ((unsigned)f2bf(acc[7]) << 16) | (unsigned)f2bf(acc[6]);
        ((uint4*)(agg + (size_t)wid * DD))[c] = r;
    }
}

// ---------------- MFMA: h_new = relu([agg,h] @ Bt + bias) -> bf16 (512 rows/block, 2 tiles) ----------------
__global__ __launch_bounds__(256) void k_mp_mfma(const unsigned short* __restrict__ Xa,
                                                 const unsigned short* __restrict__ Xh,
                                                 const unsigned short* __restrict__ Bt,
                                                 const float* __restrict__ bias,
                                                 unsigned short* __restrict__ Out) {
    __shared__ unsigned short sB[128 * 256];
    {
        const uint4* s4 = (const uint4*)Bt;
        uint4* d4 = (uint4*)sB;
        for (int i = threadIdx.x; i < 4096; i += 256) d4[i] = s4[i];
    }
    __syncthreads();
    int wave = threadIdx.x >> 6, lane = threadIdx.x & 63;
    int arow = lane & 15, kgrp = lane >> 4;
    float bcol[8];
#pragma unroll
    for (int c = 0; c < 8; ++c) bcol[c] = bias[c * 16 + arow];
#pragma unroll
    for (int tile = 0; tile < 2; ++tile) {
        int row0 = blockIdx.x * 512 + tile * 256 + wave * 64;
        f32x4 acc[4][8];
#pragma unroll
        for (int s = 0; s < 4; ++s)
#pragma unroll
            for (int c = 0; c < 8; ++c) acc[s][c] = (f32x4){0.f, 0.f, 0.f, 0.f};
        const unsigned short* aptr[4];
        const unsigned short* hptr[4];
#pragma unroll
        for (int s = 0; s < 4; ++s) {
            int r = row0 + s * 16 + arow;
            int rr = (r < MROWS) ? r : (MROWS - 1);
            aptr[s] = Xa + (size_t)rr * DD + kgrp * 8;
            hptr[s] = Xh + (size_t)rr * DD + kgrp * 8;
        }
#pragma unroll
        for (int ks = 0; ks < 8; ++ks) {
            short8 a[4];
#pragma unroll
            for (int s = 0; s < 4; ++s)
                a[s] = (ks < 4) ? *(const short8*)(aptr[s] + ks * 32)
                                : *(const short8*)(hptr[s] + (ks - 4) * 32);
#pragma unroll
            for (int c = 0; c < 8; ++c) {
                int n = c * 16 + arow;
                int mst = (ks * 4 + kgrp) ^ (n & 7);
                short8 bfr = *(const short8*)(sB + n * 256 + mst * 8);
#pragma unroll
                for (int s = 0; s < 4; ++s)
                    acc[s][c] = __builtin_amdgcn_mfma_f32_16x16x32_bf16(a[s], bfr, acc[s][c], 0, 0, 0);
            }
        }
#pragma unroll
        for (int s = 0; s < 4; ++s) {
#pragma unroll
            for (int j = 0; j < 4; ++j) {
                int r = row0 + s * 16 + kgrp * 4 + j;
                if (r < MROWS) {
                    unsigned short* orow = Out + (size_t)r * DD;
#pragma unroll
                    for (int c = 0; c < 8; ++c) {
                        float v = fmaxf(acc[s][c][j] + bcol[c], 0.f);
                        orow[c * 16 + arow] = f2bf(v);
                    }
                }
            }
        }
    }
}

// ---------------- MFMA pair+dot: logits + fused batch-max (512 rows/block, 2 tiles) ----------------
__global__ __launch_bounds__(256) void k_pair_mfma(const unsigned short* __restrict__ Xh,
                                                   const unsigned short* __restrict__ Abf,
                                                   const unsigned short* __restrict__ Bt,
                                                   const float* __restrict__ bp,
                                                   const float* __restrict__ wout,
                                                   const int* __restrict__ mc,
                                                   float* __restrict__ logits,
                                                   unsigned* __restrict__ mtrans) {
    __shared__ unsigned short sB[128 * 256];
    __shared__ unsigned smax[NB];
    {
        const uint4* s4 = (const uint4*)Bt;
        uint4* d4 = (uint4*)sB;
        for (int i = threadIdx.x; i < 4096; i += 256) d4[i] = s4[i];
        if (threadIdx.x < NB) smax[threadIdx.x] = 0u;
    }
    __syncthreads();
    int wave = threadIdx.x >> 6, lane = threadIdx.x & 63;
    int arow = lane & 15, kgrp = lane >> 4;
    float bpc[8], wc[8];
#pragma unroll
    for (int c = 0; c < 8; ++c) {
        int col = c * 16 + arow;
        bpc[c] = bp[col];
        wc[c] = wout[col];
    }
#pragma unroll
    for (int tile = 0; tile < 2; ++tile) {
        int row0 = blockIdx.x * 512 + tile * 256 + wave * 64;
        f32x4 acc[4][8];
#pragma unroll
        for (int s = 0; s < 4; ++s)
#pragma unroll
            for (int c = 0; c < 8; ++c) acc[s][c] = (f32x4){0.f, 0.f, 0.f, 0.f};
        const unsigned short* hptr[4];
        const unsigned short* aptr[4];
#pragma unroll
        for (int s = 0; s < 4; ++s) {
            int r = row0 + s * 16 + arow;
            int rr = (r < MROWS) ? r : (MROWS - 1);
            hptr[s] = Xh + (size_t)rr * DD + kgrp * 8;
            aptr[s] = Abf + (size_t)(rr / NND) * DD + kgrp * 8;
        }
#pragma unroll
        for (int ks = 0; ks < 8; ++ks) {
            short8 a[4];
#pragma unroll
            for (int s = 0; s < 4; ++s)
                a[s] = (ks < 4) ? *(const short8*)(hptr[s] + ks * 32)
                                : *(const short8*)(aptr[s] + (ks - 4) * 32);
#pragma unroll
            for (int c = 0; c < 8; ++c) {
                int n = c * 16 + arow;
                int mst = (ks * 4 + kgrp) ^ (n & 7);
                short8 bfr = *(const short8*)(sB + n * 256 + mst * 8);
#pragma unroll
                for (int s = 0; s < 4; ++s)
                    acc[s][c] = __builtin_amdgcn_mfma_f32_16x16x32_bf16(a[s], bfr, acc[s][c], 0, 0, 0);
            }
        }
#pragma unroll
        for (int s = 0; s < 4; ++s) {
#pragma unroll
            for (int j = 0; j < 4; ++j) {
                float v = 0.f;
#pragma unroll
                for (int c = 0; c < 8; ++c)
                    v += fmaxf(acc[s][c][j] + bpc[c], 0.f) * wc[c];
                v += __shfl_xor(v, 1, 64);
                v += __shfl_xor(v, 2, 64);
                v += __shfl_xor(v, 4, 64);
                v += __shfl_xor(v, 8, 64);
                int r = row0 + s * 16 + kgrp * 4 + j;
                if (arow == 0 && r < MROWS) {
                    float lv = mc[r] ? v : NEGINF;
                    logits[r] = lv;
                    atomicMax(&smax[r / NND], ftrans(lv));
                }
            }
        }
    }
    __syncthreads();
    if (threadIdx.x < NB && smax[threadIdx.x] != 0u)
        atomicMax(mtrans + threadIdx.x, smax[threadIdx.x]);
}

// ---------------- fused sumexp + context (4 rows x 16B per wave-iter) ----------------
#define CTX_CH 128
#define CTX_RPB ((NND + CTX_CH - 1) / CTX_CH)
__global__ __launch_bounds__(256) void k_ctxsum(const float* __restrict__ logits, const unsigned short* __restrict__ h,
                                                const unsigned* __restrict__ mtrans, float* S, float* ctx) {
    int b = blockIdx.x >> 7, chunk = blockIdx.x & (CTX_CH - 1);
    int rowstart = chunk * CTX_RPB;
    int rowend = min(rowstart + CTX_RPB, NND);
    int wave = threadIdx.x >> 6, lane = threadIdx.x & 63;
    int g = lane >> 4, c = lane & 15;
    float m = finv(mtrans[b]);
    float acc[8] = {0.f,0.f,0.f,0.f,0.f,0.f,0.f,0.f};
    float ws = 0.f;
    const uint4* hb = (const uint4*)(h + (size_t)b * NND * DD);
    const float* lg = logits + b * NND;
    for (int r0 = rowstart + wave * 4; r0 < rowend; r0 += 16) {
        int row = r0 + g;
        if (row < rowend) {
            float w = expf(lg[row] - m);
            ws += w;
            uint4 v = hb[row * 16 + c];
            float f[8];
            unpack8(v, f);
#pragma unroll
            for (int k = 0; k < 8; ++k) acc[k] += w * f[k];
        }
    }
#pragma unroll
    for (int k = 0; k < 8; ++k) {
        acc[k] += __shfl_xor(acc[k], 16, 64);
        acc[k] += __shfl_xor(acc[k], 32, 64);
    }
    ws += __shfl_xor(ws, 16, 64);
    ws += __shfl_xor(ws, 32, 64);
    __shared__ float sctx[4][128];
    __shared__ float sws[4];
    if (lane < 16) {
#pragma unroll
        for (int k = 0; k < 8; ++k) sctx[wave][lane * 8 + k] = acc[k];
    }
    if (lane == 0) sws[wave] = ws;
    __syncthreads();
    int tid = threadIdx.x;
    if (tid < 128) {
        float t = sctx[0][tid] + sctx[1][tid] + sctx[2][tid] + sctx[3][tid];
        atomicAdd(ctx + b * DD + tid, t);
    }
    if (tid == 0) atomicAdd(S + b, sws[0] + sws[1] + sws[2] + sws[3]);
}

// ---------------- log_probs out + value head (block 313) ----------------
__global__ __launch_bounds__(256) void k_final(const float* __restrict__ logits, const unsigned* __restrict__ mtrans,
                                               const float* __restrict__ S, const float* __restrict__ ctx,
                                               const float* __restrict__ av, const float* __restrict__ Wv,
                                               const float* __restrict__ bv, const float* __restrict__ wvo,
                                               float* __restrict__ out) {
    int tid = threadIdx.x;
    if (blockIdx.x == 313) {
        __shared__ float red[512];
#pragma unroll
        for (int half = 0; half < 2; ++half) {
            for (int t = tid; t < 2 * 256; t += 256) {
                int b = half * 2 + (t >> 7), j = t & 127;
                float sb = S[b];
                float s1 = 0.f, s2 = 0.f;
                for (int k = 0; k < 128; ++k) s1 += ctx[b * DD + k] * Wv[k * DD + j];
                for (int k = 0; k < 128; ++k) s2 += av[b * DD + k] * Wv[(128 + k) * DD + j];
                float acc = bv[j] + s1 / sb + s2;
                red[t] = fmaxf(acc, 0.f) * wvo[j];
            }
            __syncthreads();
            int j = tid & 127;
            for (int off = 64; off; off >>= 1) {
                if (j < off) {
                    red[tid] += red[tid + off];
                    red[tid + 256] += red[tid + 256 + off];
                }
                __syncthreads();
            }
            if (tid < 2) out[NB * NND + half * 2 + tid] = red[tid * 128];
            __syncthreads();
        }
        return;
    }
    int g = blockIdx.x * 256 + tid;
    if (g >= NB * NND) return;
    int b = g / NND;
    out[g] = logits[g] - finv(mtrans[b]) - logf(S[b]);
}

extern "C" void kernel_launch(void* const* d_in, const int* in_sizes, int n_in,
                              void* d_out, int out_size, void* d_ws, size_t ws_size,
                              hipStream_t stream) {
    const float* nodes = (const float*)d_in[0];
    const int* links = (const int*)d_in[1];
    const void* mask = d_in[2];
    const float* ad = (const float*)d_in[3];
    const float* Win = (const float*)d_in[4];
    const float* bin = (const float*)d_in[5];
    const float* Wm1 = (const float*)d_in[6];
    const float* Ws1 = (const float*)d_in[7];
    const float* b1 = (const float*)d_in[8];
    const float* Wm2 = (const float*)d_in[9];
    const float* Ws2 = (const float*)d_in[10];
    const float* b2 = (const float*)d_in[11];
    const float* Wad = (const float*)d_in[12];
    const float* bad = (const float*)d_in[13];
    const float* Wp = (const float*)d_in[14];
    const float* bp = (const float*)d_in[15];
    const float* wout = (const float*)d_in[16];
    const float* Wv = (const float*)d_in[17];
    const float* bv = (const float*)d_in[18];
    const float* wvo = (const float*)d_in[19];
    float* out = (float*)d_out;

    unsigned short* hA = (unsigned short*)d_ws;     // h0/h1/h2
    unsigned short* hB = hA + 10240000;             // agg
    unsigned short* B1t = hB + 10240000;
    unsigned short* B2t = B1t + 32768;
    unsigned short* Bpt = B2t + 32768;
    unsigned short* a_bf = Bpt + 32768;
    float* logits = (float*)(a_bf + 512);
    float* stats = logits + 80000;
    float* a_vec = stats + 64;
    float* Sexp = a_vec + 512;
    float* ctxb = Sexp + 64;
    unsigned* mtrans = (unsigned*)(ctxb + 512);
    int* dp = (int*)(mtrans + 64);                  // NB*NCH*NND = 1,280,000
    int* offs = dp + NB * NCH * NND;                // 80,064
    int* csr = offs + 80064;                        // 1,280,000
    int* mc = csr + 1280000;                        // 80,000
    int* flag = mc + 80000;                         // 64
    int* segsum = flag + 64;                        // 128

    k_init<<<3, 256, 0, stream>>>(stats, mtrans, Sexp, ctxb, (const unsigned char*)mask, flag);
    k_setup<<<DEGB + 256 + 313 + 3 + 1, 256, 0, stream>>>(links, dp, nodes, stats, mask, flag, mc,
                                                          Wm1, Ws1, Wm2, Ws2, Wp, B1t, B2t, Bpt,
                                                          ad, Wad, bad, a_vec, a_bf);
    k_scanA<<<NB * NSEG, 1024, 0, stream>>>(dp, offs, segsum);
    k_scanB<<<1, 64, 0, stream>>>(segsum, offs);
    k_scanC<<<NB * NSEG, 1024, 0, stream>>>(dp, offs, segsum);
    k_fill<<<DEGB, 256, 0, stream>>>(links, dp, csr);
    k_h0<<<2048, 256, 0, stream>>>(nodes, stats, Win, bin, hA);

    k_gather<<<20000, 256, 0, stream>>>(hA, offs, csr, hB);
    k_mp_mfma<<<157, 256, 0, stream>>>(hB, hA, B1t, b1, hA);
    k_gather<<<20000, 256, 0, stream>>>(hA, offs, csr, hB);
    k_mp_mfma<<<157, 256, 0, stream>>>(hB, hA, B2t, b2, hA);

    k_pair_mfma<<<157, 256, 0, stream>>>(hA, a_bf, Bpt, bp, wout, mc, logits, mtrans);
    k_ctxsum<<<NB * CTX_CH, 256, 0, stream>>>(logits, hA, mtrans, Sexp, ctxb);
    k_final<<<314, 256, 0, stream>>>(logits, mtrans, Sexp, ctxb, a_vec, Wv, bv, wvo, out);
}

// Round 15
// 254.823 us; speedup vs baseline: 1.0427x; 1.0427x over previous
//
#include <hip/hip_runtime.h>
#include <hip/hip_bf16.h>
#include <math.h>

#define NND 20000
#define NED 320000
#define NB 4
#define NFEAT 8
#define ADF 8
#define DD 128
#define MROWS (NB * NND)
#define NEGINF -1000000000.0f
#define NCH 16
#define EPC (NED / NCH)     // 20000 edges per chunk
#define NPART 8
#define PSZ (NND / NPART)   // 2500 nodes per part
#define DEGB (NB * NPART * NCH)  // 512 blocks
#define NSEG 32
#define SEGSZ (NND / NSEG)  // 625 nodes per scan segment
#define H0B 1024            // h0 blocks inside k_setup

typedef __attribute__((ext_vector_type(8))) short short8;
typedef __attribute__((ext_vector_type(4))) float f32x4;

__device__ __forceinline__ unsigned ftrans(float f) {
    unsigned u = __float_as_uint(f);
    return (u & 0x80000000u) ? ~u : (u | 0x80000000u);
}
__device__ __forceinline__ float finv(unsigned t) {
    unsigned u = (t & 0x80000000u) ? (t & 0x7fffffffu) : ~t;
    return __uint_as_float(u);
}
__device__ __forceinline__ unsigned short f2bf(float f) {  // RNE, finite inputs
    unsigned u = __float_as_uint(f);
    unsigned r = u + 0x7fffu + ((u >> 16) & 1u);
    return (unsigned short)(r >> 16);
}
__device__ __forceinline__ float bf2f(unsigned short b) {
    return __uint_as_float(((unsigned)b) << 16);
}
__device__ __forceinline__ void unpack8(uint4 v, float* f) {
    f[0] = __uint_as_float(v.x << 16); f[1] = __uint_as_float(v.x & 0xffff0000u);
    f[2] = __uint_as_float(v.y << 16); f[3] = __uint_as_float(v.y & 0xffff0000u);
    f[4] = __uint_as_float(v.z << 16); f[5] = __uint_as_float(v.z & 0xffff0000u);
    f[6] = __uint_as_float(v.w << 16); f[7] = __uint_as_float(v.w & 0xffff0000u);
}

// ---------------- init: scratch zeroing + mask flag + node stats ----------------
// blocks [0,2]: zero-init + flag; [3,259): node stats (needs only `nodes`).
__global__ __launch_bounds__(256) void k_init(float* stats, unsigned* mtrans, float* S, float* ctx,
                                              const unsigned char* __restrict__ m, int* flag,
                                              const float* __restrict__ nodes) {
    int bid = blockIdx.x, tid = threadIdx.x;
    if (bid == 2) {
        __shared__ int any;
        if (tid == 0) any = 0;
        __syncthreads();
        int found = 0;
        for (int p = tid; p < 4096; p += 256)
            if ((p & 3) && m[p]) found = 1;
        if (found) atomicOr(&any, 1);
        __syncthreads();
        if (tid == 0) *flag = any;
        return;
    }
    if (bid < 2) {
        int i = bid * 256 + tid;
        if (i < 16) stats[i] = 0.f;   // note: stats written before stats-blocks atomically add (they're in this same kernel -> need care)
        if (i < NB) { mtrans[i] = 0u; S[i] = 0.f; }
        if (i < NB * DD) ctx[i] = 0.f;
        return;
    }
    // stats phase: blocks [3, 259) -- 256 blocks. stats[] zeroed by block 0 -- RACE!
    // To avoid intra-kernel race on stats zeroing, stats blocks accumulate into
    // stats[16..47] partials by block-group instead, summed in k_setup's h0 phase? 
    // Simpler: stats blocks use atomicAdd on stats[0..15] but zeroing happens in
    // the same kernel. Fix: stats zeroed here by EACH stats block? No.
    // Resolution: stats[] is zeroed by the HOST-side trick: we instead compute
    // partial sums per block into stats[16 + (bid-3)*0 .. ] -- too complex.
    // Final design: stats blocks write block-partials with atomicAdd into
    // stats[16..31] (sums) and stats[32..47] (sumsq), which were zeroed in the
    // PREVIOUS kernel? There is no previous kernel.
    // -> We accept one extra dispatch instead: this branch never taken (grid=3).
}

// ---------------- stats kernel (separate, 256 blocks) ----------------
__global__ __launch_bounds__(256) void k_stats(const float* __restrict__ nodes, float* stats) {
    int tid = threadIdx.x;
    int gid = blockIdx.x * 256 + tid;
    float s[8] = {0.f,0.f,0.f,0.f,0.f,0.f,0.f,0.f};
    float q[8] = {0.f,0.f,0.f,0.f,0.f,0.f,0.f,0.f};
    for (int r = gid; r < NB * NND; r += 256 * 256) {
        const float* p = nodes + (size_t)r * NFEAT;
#pragma unroll
        for (int k = 0; k < 8; ++k) { float v = p[k]; s[k] += v; q[k] += v * v; }
    }
#pragma unroll
    for (int k = 0; k < 8; ++k) {
        for (int off = 32; off; off >>= 1) {
            s[k] += __shfl_xor(s[k], off, 64);
            q[k] += __shfl_xor(q[k], off, 64);
        }
    }
    __shared__ float ls[4][16];
    int w = tid >> 6, lane = tid & 63;
    if (lane == 0) {
#pragma unroll
        for (int k = 0; k < 8; ++k) { ls[w][k] = s[k]; ls[w][8 + k] = q[k]; }
    }
    __syncthreads();
    if (tid < 16) {
        float t = ls[0][tid] + ls[1][tid] + ls[2][tid] + ls[3][tid];
        atomicAdd(stats + tid, t);
    }
}

// ---------------- fused setup: deg-partials + h0 + maskc + prep + ad ----------------
// Requires stats complete (k_stats ran before). blocks:
// [0,DEGB): deg histograms; [DEGB, DEGB+H0B): h0; then maskc(313), prep(3), ad(1).
__global__ __launch_bounds__(256) void k_setup(const int* __restrict__ links, int* __restrict__ dp,
                                               const float* __restrict__ nodes, const float* __restrict__ stats,
                                               const float* __restrict__ Win, const float* __restrict__ bin,
                                               unsigned short* __restrict__ h,
                                               const void* __restrict__ m, const int* __restrict__ flag,
                                               int* __restrict__ mc,
                                               const float* __restrict__ Wm1, const float* __restrict__ Ws1,
                                               const float* __restrict__ Wm2, const float* __restrict__ Ws2,
                                               const float* __restrict__ Wp,
                                               unsigned short* __restrict__ B1t, unsigned short* __restrict__ B2t,
                                               unsigned short* __restrict__ Bpt,
                                               const float* __restrict__ ad, const float* __restrict__ Wad,
                                               const float* __restrict__ bad, float* __restrict__ av,
                                               unsigned short* __restrict__ av_bf) {
    int bid = blockIdx.x, tid = threadIdx.x;
    if (bid < DEGB) {
        __shared__ int hist[PSZ];  // 10 KiB
        int part = bid & 7;
        int b = (bid >> 3) & 3;
        int c = bid >> 5;
        const int lo = part * PSZ;
        for (int i = tid; i < PSZ; i += 256) hist[i] = 0;
        __syncthreads();
        const int4* dstp4 = (const int4*)(links + b * 2 * NED + NED + c * EPC);
        for (int q = tid; q < EPC / 4; q += 256) {
            int4 d = dstp4[q];
            if (d.x >= lo && d.x < lo + PSZ) atomicAdd(&hist[d.x - lo], 1);
            if (d.y >= lo && d.y < lo + PSZ) atomicAdd(&hist[d.y - lo], 1);
            if (d.z >= lo && d.z < lo + PSZ) atomicAdd(&hist[d.z - lo], 1);
            if (d.w >= lo && d.w < lo + PSZ) atomicAdd(&hist[d.w - lo], 1);
        }
        __syncthreads();
        int* out = dp + (size_t)(b * NCH + c) * NND + lo;
        for (int i = tid; i < PSZ; i += 256) out[i] = hist[i];
        return;
    }
    if (bid < DEGB + H0B) {
        __shared__ float sW[NFEAT * DD];
        __shared__ float sb[DD];
        __shared__ float sm[8], sr[8];
        for (int i = tid; i < NFEAT * DD; i += 256) sW[i] = Win[i];
        if (tid < DD) sb[tid] = bin[tid];
        if (tid < 8) {
            float inv_n = 1.f / (float)(NB * NND);
            float mean = stats[tid] * inv_n;
            float var = stats[8 + tid] * inv_n - mean * mean;
            var = fmaxf(var, 0.f);
            sm[tid] = mean;
            sr[tid] = 1.f / (sqrtf(var) + 1e-8f);
        }
        __syncthreads();
        for (int t = (bid - DEGB) * 256 + tid; t < NB * NND * 16; t += H0B * 256) {
            int bn = t >> 4;
            int j0 = (t & 15) << 3;
            const float* p = nodes + (size_t)bn * NFEAT;
            float acc[8];
#pragma unroll
            for (int jj = 0; jj < 8; ++jj) acc[jj] = sb[j0 + jj];
#pragma unroll
            for (int k = 0; k < 8; ++k) {
                float x = (p[k] - sm[k]) * sr[k];
#pragma unroll
                for (int jj = 0; jj < 8; ++jj) acc[jj] += x * sW[k * DD + j0 + jj];
            }
            uint4 r;
            r.x = ((unsigned)f2bf(fmaxf(acc[1], 0.f)) << 16) | (unsigned)f2bf(fmaxf(acc[0], 0.f));
            r.y = ((unsigned)f2bf(fmaxf(acc[3], 0.f)) << 16) | (unsigned)f2bf(fmaxf(acc[2], 0.f));
            r.z = ((unsigned)f2bf(fmaxf(acc[5], 0.f)) << 16) | (unsigned)f2bf(fmaxf(acc[4], 0.f));
            r.w = ((unsigned)f2bf(fmaxf(acc[7], 0.f)) << 16) | (unsigned)f2bf(fmaxf(acc[6], 0.f));
            *(uint4*)(h + (size_t)bn * DD + j0) = r;
        }
        return;
    }
    if (bid < DEGB + H0B + 313) {
        int g = (bid - DEGB - H0B) * 256 + tid;
        if (g < NB * NND) {
            int f = *flag;
            mc[g] = f ? (int)((const unsigned char*)m)[g] : ((const int*)m)[g];
        }
        return;
    }
    if (bid < DEGB + H0B + 313 + 3) {
        int mtx = bid - (DEGB + H0B + 313);
        const float* S0 = (mtx == 0) ? Wm1 : ((mtx == 1) ? Wm2 : Wp);
        const float* S1 = (mtx == 0) ? Ws1 : ((mtx == 1) ? Ws2 : (Wp + 128 * DD));
        unsigned short* D = (mtx == 0) ? B1t : ((mtx == 1) ? B2t : Bpt);
        for (int idx = tid; idx < 128 * 32; idx += 256) {
            int n = idx >> 5;
            int mm = idx & 31;
            short8 pk;
#pragma unroll
            for (int j = 0; j < 8; ++j) {
                int k = mm * 8 + j;
                float v = (k < 128) ? S0[k * DD + n] : S1[(k - 128) * DD + n];
                pk[j] = (short)f2bf(v);
            }
            int mst = mm ^ (n & 7);
            *(short8*)(D + n * 256 + mst * 8) = pk;
        }
        return;
    }
    // ad head (1 block)
    __shared__ float sn[NB * ADF];
    if (tid < ADF) {
        float mm = 0.f;
        for (int b = 0; b < NB; ++b) mm += ad[b * ADF + tid];
        mm *= 0.25f;
        float v = 0.f;
        for (int b = 0; b < NB; ++b) { float d = ad[b * ADF + tid] - mm; v += d * d; }
        v *= 0.25f;
        float r = 1.f / (sqrtf(v) + 1e-8f);
        for (int b = 0; b < NB; ++b) sn[b * ADF + tid] = (ad[b * ADF + tid] - mm) * r;
    }
    __syncthreads();
    for (int t = tid; t < NB * DD; t += 256) {
        int b = t >> 7, j = t & 127;
        float acc = bad[j];
#pragma unroll
        for (int k = 0; k < 8; ++k) acc += sn[b * ADF + k] * Wad[k * DD + j];
        float rl = fmaxf(acc, 0.f);
        av[t] = rl;
        av_bf[t] = f2bf(rl);
    }
}

// ---------------- 3-phase parallel scan ----------------
__global__ __launch_bounds__(1024) void k_scanA(const int* __restrict__ dp, int* __restrict__ offs,
                                                int* __restrict__ segsum) {
    int b = blockIdx.x >> 5, seg = blockIdx.x & 31;
    int tid = threadIdx.x, lane = tid & 63, wv = tid >> 6;
    __shared__ int wsum[16], wexcl[16];
    int i = seg * SEGSZ + tid;
    int v = 0;
    if (tid < SEGSZ) {
#pragma unroll
        for (int q = 0; q < NCH; ++q) v += dp[(size_t)(b * NCH + q) * NND + i];
    }
    int x = v;
#pragma unroll
    for (int d = 1; d < 64; d <<= 1) {
        int t = __shfl_up(x, d, 64);
        if (lane >= d) x += t;
    }
    if (lane == 63) wsum[wv] = x;
    __syncthreads();
    if (wv == 0) {
        int s = (lane < 16) ? wsum[lane] : 0;
#pragma unroll
        for (int d = 1; d < 16; d <<= 1) {
            int t = __shfl_up(s, d, 64);
            if (lane >= d) s += t;
        }
        if (lane < 16) wexcl[lane] = s - wsum[lane];
    }
    __syncthreads();
    int excl = wexcl[wv] + (x - v);
    if (tid < SEGSZ) offs[b * (NND + 1) + i] = excl;
    if (tid == SEGSZ - 1) segsum[blockIdx.x] = excl + v;
}

__global__ void k_scanB(int* __restrict__ segsum, int* __restrict__ offs) {
    int tid = threadIdx.x;
    if (tid < NB) {
        int run = 0;
        for (int s = 0; s < NSEG; ++s) {
            int t = segsum[tid * NSEG + s];
            segsum[tid * NSEG + s] = run;
            run += t;
        }
        offs[tid * (NND + 1) + NND] = run;
    }
}

__global__ __launch_bounds__(1024) void k_scanC(int* __restrict__ dp, int* __restrict__ offs,
                                                const int* __restrict__ segsum) {
    int b = blockIdx.x >> 5, seg = blockIdx.x & 31;
    int tid = threadIdx.x;
    if (tid >= SEGSZ) return;
    int i = seg * SEGSZ + tid;
    int excl = segsum[blockIdx.x] + offs[b * (NND + 1) + i];
    offs[b * (NND + 1) + i] = excl;
    int run = excl;
#pragma unroll
    for (int q = 0; q < NCH; ++q) {
        size_t a = (size_t)(b * NCH + q) * NND + i;
        int p = dp[a];
        dp[a] = run;
        run += p;
    }
}

// ---------------- CSR fill via LDS cursors ----------------
__global__ __launch_bounds__(256) void k_fill(const int* __restrict__ links, const int* __restrict__ dp,
                                              int* __restrict__ csr) {
    __shared__ int cur[PSZ];  // 10 KiB
    int bid = blockIdx.x, tid = threadIdx.x;
    int part = bid & 7;
    int b = (bid >> 3) & 3;
    int c = bid >> 5;
    const int lo = part * PSZ;
    const int* cstart = dp + (size_t)(b * NCH + c) * NND + lo;
    for (int i = tid; i < PSZ; i += 256) cur[i] = cstart[i];
    __syncthreads();
    const int4* dstp4 = (const int4*)(links + b * 2 * NED + NED + c * EPC);
    const int* srcp = links + b * 2 * NED + c * EPC;
    int* cs = csr + (size_t)b * NED;
    for (int q = tid; q < EPC / 4; q += 256) {
        int4 d = dstp4[q];
        int e = q * 4;
        if (d.x >= lo && d.x < lo + PSZ) { int pos = atomicAdd(&cur[d.x - lo], 1); cs[pos] = srcp[e]; }
        if (d.y >= lo && d.y < lo + PSZ) { int pos = atomicAdd(&cur[d.y - lo], 1); cs[pos] = srcp[e + 1]; }
        if (d.z >= lo && d.z < lo + PSZ) { int pos = atomicAdd(&cur[d.z - lo], 1); cs[pos] = srcp[e + 2]; }
        if (d.w >= lo && d.w < lo + PSZ) { int pos = atomicAdd(&cur[d.w - lo], 1); cs[pos] = srcp[e + 3]; }
    }
}

// ---------------- agg[n] = sum_{src->n} h[src]  (wave/node + XCD-batch affinity, pipelined) ----------------
__global__ __launch_bounds__(256) void k_gather(const unsigned short* __restrict__ h, const int* __restrict__ offs,
                                                const int* __restrict__ csr, unsigned short* __restrict__ agg) {
    int bid = blockIdx.x;
    int xcd = bid & 7;
    int b = xcd >> 1;
    int sub = (bid >> 3) * 2 + (xcd & 1);
    int n = sub * 4 + (threadIdx.x >> 6);
    int lane = threadIdx.x & 63;
    if (n >= NND) return;
    int wid = b * NND + n;
    int off0 = offs[b * (NND + 1) + n];
    int off1 = offs[b * (NND + 1) + n + 1];
    int g = lane >> 4, c = lane & 15;
    float acc[8] = {0.f,0.f,0.f,0.f,0.f,0.f,0.f,0.f};
    const uint4* hb = (const uint4*)(h + (size_t)b * NND * DD);
    const int* cs = csr + (size_t)b * NED;
    for (int base = off0; base < off1; base += 64) {
        int cnt = min(64, off1 - base);
        int idx = (lane < cnt) ? cs[base + lane] : 0;
        int full = cnt >> 2;
        if (full > 0) {
            int srcn = __shfl(idx, g, 64);
            uint4 v = hb[srcn * 16 + c];
            for (int j = 1; j < full; ++j) {
                int srcn2 = __shfl(idx, j * 4 + g, 64);
                uint4 v2 = hb[srcn2 * 16 + c];
                float f[8];
                unpack8(v, f);
#pragma unroll
                for (int k = 0; k < 8; ++k) acc[k] += f[k];
                v = v2;
            }
            float f[8];
            unpack8(v, f);
#pragma unroll
            for (int k = 0; k < 8; ++k) acc[k] += f[k];
        }
        int q = full * 4 + g;
        int srcn = __shfl(idx, q, 64);
        if (q < cnt) {
            uint4 v = hb[srcn * 16 + c];
            float f[8];
            unpack8(v, f);
#pragma unroll
            for (int k = 0; k < 8; ++k) acc[k] += f[k];
        }
    }
#pragma unroll
    for (int k = 0; k < 8; ++k) {
        acc[k] += __shfl_xor(acc[k], 16, 64);
        acc[k] += __shfl_xor(acc[k], 32, 64);
    }
    if (lane < 16) {
        uint4 r;
        r.x = ((unsigned)f2bf(acc[1]) << 16) | (unsigned)f2bf(acc[0]);
        r.y = ((unsigned)f2bf(acc[3]) << 16) | (unsigned)f2bf(acc[2]);
        r.z = ((unsigned)f2bf(acc[5]) << 16) | (unsigned)f2bf(acc[4]);
        r.w = ((unsigned)f2bf(acc[7]) << 16) | (unsigned)f2bf(acc[6]);
        ((uint4*)(agg + (size_t)wid * DD))[c] = r;
    }
}

// ---------------- MFMA: h_new = relu([agg,h] @ Bt + bias) -> bf16 (256 rows/block) ----------------
__global__ __launch_bounds__(256) void k_mp_mfma(const unsigned short* __restrict__ Xa,
                                                 const unsigned short* __restrict__ Xh,
                                                 const unsigned short* __restrict__ Bt,
                                                 const float* __restrict__ bias,
                                                 unsigned short* __restrict__ Out) {
    __shared__ unsigned short sB[128 * 256];
    {
        const uint4* s4 = (const uint4*)Bt;
        uint4* d4 = (uint4*)sB;
        for (int i = threadIdx.x; i < 4096; i += 256) d4[i] = s4[i];
    }
    __syncthreads();
    int wave = threadIdx.x >> 6, lane = threadIdx.x & 63;
    int row0 = blockIdx.x * 256 + wave * 64;
    int arow = lane & 15, kgrp = lane >> 4;
    f32x4 acc[4][8];
#pragma unroll
    for (int s = 0; s < 4; ++s)
#pragma unroll
        for (int c = 0; c < 8; ++c) acc[s][c] = (f32x4){0.f, 0.f, 0.f, 0.f};
    const unsigned short* aptr[4];
    const unsigned short* hptr[4];
#pragma unroll
    for (int s = 0; s < 4; ++s) {
        int r = row0 + s * 16 + arow;
        int rr = (r < MROWS) ? r : (MROWS - 1);
        aptr[s] = Xa + (size_t)rr * DD + kgrp * 8;
        hptr[s] = Xh + (size_t)rr * DD + kgrp * 8;
    }
#pragma unroll
    for (int ks = 0; ks < 8; ++ks) {
        short8 a[4];
#pragma unroll
        for (int s = 0; s < 4; ++s)
            a[s] = (ks < 4) ? *(const short8*)(aptr[s] + ks * 32)
                            : *(const short8*)(hptr[s] + (ks - 4) * 32);
#pragma unroll
        for (int c = 0; c < 8; ++c) {
            int n = c * 16 + arow;
            int mst = (ks * 4 + kgrp) ^ (n & 7);
            short8 bfr = *(const short8*)(sB + n * 256 + mst * 8);
#pragma unroll
            for (int s = 0; s < 4; ++s)
                acc[s][c] = __builtin_amdgcn_mfma_f32_16x16x32_bf16(a[s], bfr, acc[s][c], 0, 0, 0);
        }
    }
    float bcol[8];
#pragma unroll
    for (int c = 0; c < 8; ++c) bcol[c] = bias[c * 16 + arow];
#pragma unroll
    for (int s = 0; s < 4; ++s) {
#pragma unroll
        for (int j = 0; j < 4; ++j) {
            int r = row0 + s * 16 + kgrp * 4 + j;
            if (r < MROWS) {
                unsigned short* orow = Out + (size_t)r * DD;
#pragma unroll
                for (int c = 0; c < 8; ++c) {
                    float v = fmaxf(acc[s][c][j] + bcol[c], 0.f);
                    orow[c * 16 + arow] = f2bf(v);
                }
            }
        }
    }
}

// ---------------- MFMA pair+dot: logits + fused batch-max (256 rows/block) ----------------
__global__ __launch_bounds__(256) void k_pair_mfma(const unsigned short* __restrict__ Xh,
                                                   const unsigned short* __restrict__ Abf,
                                                   const unsigned short* __restrict__ Bt,
                                                   const float* __restrict__ bp,
                                                   const float* __restrict__ wout,
                                                   const int* __restrict__ mc,
                                                   float* __restrict__ logits,
                                                   unsigned* __restrict__ mtrans) {
    __shared__ unsigned short sB[128 * 256];
    __shared__ unsigned smax[NB];
    {
        const uint4* s4 = (const uint4*)Bt;
        uint4* d4 = (uint4*)sB;
        for (int i = threadIdx.x; i < 4096; i += 256) d4[i] = s4[i];
        if (threadIdx.x < NB) smax[threadIdx.x] = 0u;
    }
    __syncthreads();
    int wave = threadIdx.x >> 6, lane = threadIdx.x & 63;
    int row0 = blockIdx.x * 256 + wave * 64;
    int arow = lane & 15, kgrp = lane >> 4;
    f32x4 acc[4][8];
#pragma unroll
    for (int s = 0; s < 4; ++s)
#pragma unroll
        for (int c = 0; c < 8; ++c) acc[s][c] = (f32x4){0.f, 0.f, 0.f, 0.f};
    const unsigned short* hptr[4];
    const unsigned short* aptr[4];
#pragma unroll
    for (int s = 0; s < 4; ++s) {
        int r = row0 + s * 16 + arow;
        int rr = (r < MROWS) ? r : (MROWS - 1);
        hptr[s] = Xh + (size_t)rr * DD + kgrp * 8;
        aptr[s] = Abf + (size_t)(rr / NND) * DD + kgrp * 8;
    }
#pragma unroll
    for (int ks = 0; ks < 8; ++ks) {
        short8 a[4];
#pragma unroll
        for (int s = 0; s < 4; ++s)
            a[s] = (ks < 4) ? *(const short8*)(hptr[s] + ks * 32)
                            : *(const short8*)(aptr[s] + (ks - 4) * 32);
#pragma unroll
        for (int c = 0; c < 8; ++c) {
            int n = c * 16 + arow;
            int mst = (ks * 4 + kgrp) ^ (n & 7);
            short8 bfr = *(const short8*)(sB + n * 256 + mst * 8);
#pragma unroll
            for (int s = 0; s < 4; ++s)
                acc[s][c] = __builtin_amdgcn_mfma_f32_16x16x32_bf16(a[s], bfr, acc[s][c], 0, 0, 0);
        }
    }
    float bpc[8], wc[8];
#pragma unroll
    for (int c = 0; c < 8; ++c) {
        int col = c * 16 + arow;
        bpc[c] = bp[col];
        wc[c] = wout[col];
    }
#pragma unroll
    for (int s = 0; s < 4; ++s) {
#pragma unroll
        for (int j = 0; j < 4; ++j) {
            float v = 0.f;
#pragma unroll
            for (int c = 0; c < 8; ++c)
                v += fmaxf(acc[s][c][j] + bpc[c], 0.f) * wc[c];
            v += __shfl_xor(v, 1, 64);
            v += __shfl_xor(v, 2, 64);
            v += __shfl_xor(v, 4, 64);
            v += __shfl_xor(v, 8, 64);
            int r = row0 + s * 16 + kgrp * 4 + j;
            if (arow == 0 && r < MROWS) {
                float lv = mc[r] ? v : NEGINF;
                logits[r] = lv;
                atomicMax(&smax[r / NND], ftrans(lv));
            }
        }
    }
    __syncthreads();
    if (threadIdx.x < NB && smax[threadIdx.x] != 0u)
        atomicMax(mtrans + threadIdx.x, smax[threadIdx.x]);
}

// ---------------- fused sumexp + context ----------------
#define CTX_CH 128
#define CTX_RPB ((NND + CTX_CH - 1) / CTX_CH)
__global__ __launch_bounds__(256) void k_ctxsum(const float* __restrict__ logits, const unsigned short* __restrict__ h,
                                                const unsigned* __restrict__ mtrans, float* S, float* ctx) {
    int b = blockIdx.x >> 7, chunk = blockIdx.x & (CTX_CH - 1);
    int rowstart = chunk * CTX_RPB;
    int rowend = min(rowstart + CTX_RPB, NND);
    int wave = threadIdx.x >> 6, lane = threadIdx.x & 63;
    int g = lane >> 4, c = lane & 15;
    float m = finv(mtrans[b]);
    float acc[8] = {0.f,0.f,0.f,0.f,0.f,0.f,0.f,0.f};
    float ws = 0.f;
    const uint4* hb = (const uint4*)(h + (size_t)b * NND * DD);
    const float* lg = logits + b * NND;
    for (int r0 = rowstart + wave * 4; r0 < rowend; r0 += 16) {
        int row = r0 + g;
        if (row < rowend) {
            float w = expf(lg[row] - m);
            ws += w;
            uint4 v = hb[row * 16 + c];
            float f[8];
            unpack8(v, f);
#pragma unroll
            for (int k = 0; k < 8; ++k) acc[k] += w * f[k];
        }
    }
#pragma unroll
    for (int k = 0; k < 8; ++k) {
        acc[k] += __shfl_xor(acc[k], 16, 64);
        acc[k] += __shfl_xor(acc[k], 32, 64);
    }
    ws += __shfl_xor(ws, 16, 64);
    ws += __shfl_xor(ws, 32, 64);
    __shared__ float sctx[4][128];
    __shared__ float sws[4];
    if (lane < 16) {
#pragma unroll
        for (int k = 0; k < 8; ++k) sctx[wave][lane * 8 + k] = acc[k];
    }
    if (lane == 0) sws[wave] = ws;
    __syncthreads();
    int tid = threadIdx.x;
    if (tid < 128) {
        float t = sctx[0][tid] + sctx[1][tid] + sctx[2][tid] + sctx[3][tid];
        atomicAdd(ctx + b * DD + tid, t);
    }
    if (tid == 0) atomicAdd(S + b, sws[0] + sws[1] + sws[2] + sws[3]);
}

// ---------------- log_probs out + value head (block 313) ----------------
__global__ __launch_bounds__(256) void k_final(const float* __restrict__ logits, const unsigned* __restrict__ mtrans,
                                               const float* __restrict__ S, const float* __restrict__ ctx,
                                               const float* __restrict__ av, const float* __restrict__ Wv,
                                               const float* __restrict__ bv, const float* __restrict__ wvo,
                                               float* __restrict__ out) {
    int tid = threadIdx.x;
    if (blockIdx.x == 313) {
        __shared__ float red[512];
#pragma unroll
        for (int half = 0; half < 2; ++half) {
            for (int t = tid; t < 2 * 256; t += 256) {
                int b = half * 2 + (t >> 7), j = t & 127;
                float sb = S[b];
                float s1 = 0.f, s2 = 0.f;
                for (int k = 0; k < 128; ++k) s1 += ctx[b * DD + k] * Wv[k * DD + j];
                for (int k = 0; k < 128; ++k) s2 += av[b * DD + k] * Wv[(128 + k) * DD + j];
                float acc = bv[j] + s1 / sb + s2;
                red[t] = fmaxf(acc, 0.f) * wvo[j];
            }
            __syncthreads();
            int j = tid & 127;
            for (int off = 64; off; off >>= 1) {
                if (j < off) {
                    red[tid] += red[tid + off];
                    red[tid + 256] += red[tid + 256 + off];
                }
                __syncthreads();
            }
            if (tid < 2) out[NB * NND + half * 2 + tid] = red[tid * 128];
            __syncthreads();
        }
        return;
    }
    int g = blockIdx.x * 256 + tid;
    if (g >= NB * NND) return;
    int b = g / NND;
    out[g] = logits[g] - finv(mtrans[b]) - logf(S[b]);
}

extern "C" void kernel_launch(void* const* d_in, const int* in_sizes, int n_in,
                              void* d_out, int out_size, void* d_ws, size_t ws_size,
                              hipStream_t stream) {
    const float* nodes = (const float*)d_in[0];
    const int* links = (const int*)d_in[1];
    const void* mask = d_in[2];
    const float* ad = (const float*)d_in[3];
    const float* Win = (const float*)d_in[4];
    const float* bin = (const float*)d_in[5];
    const float* Wm1 = (const float*)d_in[6];
    const float* Ws1 = (const float*)d_in[7];
    const float* b1 = (const float*)d_in[8];
    const float* Wm2 = (const float*)d_in[9];
    const float* Ws2 = (const float*)d_in[10];
    const float* b2 = (const float*)d_in[11];
    const float* Wad = (const float*)d_in[12];
    const float* bad = (const float*)d_in[13];
    const float* Wp = (const float*)d_in[14];
    const float* bp = (const float*)d_in[15];
    const float* wout = (const float*)d_in[16];
    const float* Wv = (const float*)d_in[17];
    const float* bv = (const float*)d_in[18];
    const float* wvo = (const float*)d_in[19];
    float* out = (float*)d_out;

    unsigned short* hA = (unsigned short*)d_ws;     // h0/h1/h2
    unsigned short* hB = hA + 10240000;             // agg
    unsigned short* B1t = hB + 10240000;
    unsigned short* B2t = B1t + 32768;
    unsigned short* Bpt = B2t + 32768;
    unsigned short* a_bf = Bpt + 32768;
    float* logits = (float*)(a_bf + 512);
    float* stats = logits + 80000;
    float* a_vec = stats + 64;
    float* Sexp = a_vec + 512;
    float* ctxb = Sexp + 64;
    unsigned* mtrans = (unsigned*)(ctxb + 512);
    int* dp = (int*)(mtrans + 64);                  // NB*NCH*NND = 1,280,000
    int* offs = dp + NB * NCH * NND;                // 80,064
    int* csr = offs + 80064;                        // 1,280,000
    int* mc = csr + 1280000;                        // 80,000
    int* flag = mc + 80000;                         // 64
    int* segsum = flag + 64;                        // 128

    k_init<<<3, 256, 0, stream>>>(stats, mtrans, Sexp, ctxb, (const unsigned char*)mask, flag, nodes);
    k_stats<<<256, 256, 0, stream>>>(nodes, stats);
    k_setup<<<DEGB + H0B + 313 + 3 + 1, 256, 0, stream>>>(links, dp, nodes, stats, Win, bin, hA,
                                                          mask, flag, mc,
                                                          Wm1, Ws1, Wm2, Ws2, Wp, B1t, B2t, Bpt,
                                                          ad, Wad, bad, a_vec, a_bf);
    k_scanA<<<NB * NSEG, 1024, 0, stream>>>(dp, offs, segsum);
    k_scanB<<<1, 64, 0, stream>>>(segsum, offs);
    k_scanC<<<NB * NSEG, 1024, 0, stream>>>(dp, offs, segsum);
    k_fill<<<DEGB, 256, 0, stream>>>(links, dp, csr);

    k_gather<<<20000, 256, 0, stream>>>(hA, offs, csr, hB);
    k_mp_mfma<<<313, 256, 0, stream>>>(hB, hA, B1t, b1, hA);
    k_gather<<<20000, 256, 0, stream>>>(hA, offs, csr, hB);
    k_mp_mfma<<<313, 256, 0, stream>>>(hB, hA, B2t, b2, hA);

    k_pair_mfma<<<313, 256, 0, stream>>>(hA, a_bf, Bpt, bp, wout, mc, logits, mtrans);
    k_ctxsum<<<NB * CTX_CH, 256, 0, stream>>>(logits, hA, mtrans, Sexp, ctxb);
    k_final<<<314, 256, 0, stream>>>(logits, mtrans, Sexp, ctxb, a_vec, Wv, bv, wvo, out);
}

// Round 16
// 238.050 us; speedup vs baseline: 1.1161x; 1.0705x over previous
//
#include <hip/hip_runtime.h>
#include <hip/hip_bf16.h>
#include <math.h>

#define NND 20000
#define NED 320000
#define NB 4
#define NFEAT 8
#define ADF 8
#define DD 128
#define MROWS (NB * NND)
#define NEGINF -1000000000.0f
#define NCH 32
#define EPC (NED / NCH)     // 10000 edges per chunk
#define NPART 4
#define PSZ (NND / NPART)   // 5000 nodes per part (20 KiB LDS)
#define DEGB (NB * NPART * NCH)  // 512 blocks
#define NSEG 32
#define SEGSZ (NND / NSEG)  // 625 nodes per scan segment
#define H0B 1024            // h0 blocks inside k_setup

typedef __attribute__((ext_vector_type(8))) short short8;
typedef __attribute__((ext_vector_type(4))) float f32x4;

__device__ __forceinline__ unsigned ftrans(float f) {
    unsigned u = __float_as_uint(f);
    return (u & 0x80000000u) ? ~u : (u | 0x80000000u);
}
__device__ __forceinline__ float finv(unsigned t) {
    unsigned u = (t & 0x80000000u) ? (t & 0x7fffffffu) : ~t;
    return __uint_as_float(u);
}
__device__ __forceinline__ unsigned short f2bf(float f) {  // RNE, finite inputs
    unsigned u = __float_as_uint(f);
    unsigned r = u + 0x7fffu + ((u >> 16) & 1u);
    return (unsigned short)(r >> 16);
}
__device__ __forceinline__ float bf2f(unsigned short b) {
    return __uint_as_float(((unsigned)b) << 16);
}
__device__ __forceinline__ void unpack8(uint4 v, float* f) {
    f[0] = __uint_as_float(v.x << 16); f[1] = __uint_as_float(v.x & 0xffff0000u);
    f[2] = __uint_as_float(v.y << 16); f[3] = __uint_as_float(v.y & 0xffff0000u);
    f[4] = __uint_as_float(v.z << 16); f[5] = __uint_as_float(v.z & 0xffff0000u);
    f[6] = __uint_as_float(v.w << 16); f[7] = __uint_as_float(v.w & 0xffff0000u);
}

// ---------------- init: scratch zeroing + mask flag ----------------
__global__ __launch_bounds__(256) void k_init(float* stats, unsigned* mtrans, float* S, float* ctx,
                                              const unsigned char* __restrict__ m, int* flag) {
    int bid = blockIdx.x, tid = threadIdx.x;
    if (bid == 2) {
        __shared__ int any;
        if (tid == 0) any = 0;
        __syncthreads();
        int found = 0;
        for (int p = tid; p < 4096; p += 256)
            if ((p & 3) && m[p]) found = 1;
        if (found) atomicOr(&any, 1);
        __syncthreads();
        if (tid == 0) *flag = any;
        return;
    }
    int i = bid * 256 + tid;
    if (i < 16) stats[i] = 0.f;
    if (i < NB) { mtrans[i] = 0u; S[i] = 0.f; }
    if (i < NB * DD) ctx[i] = 0.f;
}

// ---------------- stats kernel (256 blocks) ----------------
__global__ __launch_bounds__(256) void k_stats(const float* __restrict__ nodes, float* stats) {
    int tid = threadIdx.x;
    int gid = blockIdx.x * 256 + tid;
    float s[8] = {0.f,0.f,0.f,0.f,0.f,0.f,0.f,0.f};
    float q[8] = {0.f,0.f,0.f,0.f,0.f,0.f,0.f,0.f};
    for (int r = gid; r < NB * NND; r += 256 * 256) {
        const float* p = nodes + (size_t)r * NFEAT;
#pragma unroll
        for (int k = 0; k < 8; ++k) { float v = p[k]; s[k] += v; q[k] += v * v; }
    }
#pragma unroll
    for (int k = 0; k < 8; ++k) {
        for (int off = 32; off; off >>= 1) {
            s[k] += __shfl_xor(s[k], off, 64);
            q[k] += __shfl_xor(q[k], off, 64);
        }
    }
    __shared__ float ls[4][16];
    int w = tid >> 6, lane = tid & 63;
    if (lane == 0) {
#pragma unroll
        for (int k = 0; k < 8; ++k) { ls[w][k] = s[k]; ls[w][8 + k] = q[k]; }
    }
    __syncthreads();
    if (tid < 16) {
        float t = ls[0][tid] + ls[1][tid] + ls[2][tid] + ls[3][tid];
        atomicAdd(stats + tid, t);
    }
}

// ---------------- fused setup: deg-partials + h0 + maskc + prep + ad ----------------
// blocks [0,DEGB): deg histograms (part=bid&3, b=(bid>>2)&3, c=bid>>4);
// [DEGB,DEGB+H0B): h0; then maskc(313), prep(3), ad(1).
__global__ __launch_bounds__(256) void k_setup(const int* __restrict__ links, int* __restrict__ dp,
                                               const float* __restrict__ nodes, const float* __restrict__ stats,
                                               const float* __restrict__ Win, const float* __restrict__ bin,
                                               unsigned short* __restrict__ h,
                                               const void* __restrict__ m, const int* __restrict__ flag,
                                               int* __restrict__ mc,
                                               const float* __restrict__ Wm1, const float* __restrict__ Ws1,
                                               const float* __restrict__ Wm2, const float* __restrict__ Ws2,
                                               const float* __restrict__ Wp,
                                               unsigned short* __restrict__ B1t, unsigned short* __restrict__ B2t,
                                               unsigned short* __restrict__ Bpt,
                                               const float* __restrict__ ad, const float* __restrict__ Wad,
                                               const float* __restrict__ bad, float* __restrict__ av,
                                               unsigned short* __restrict__ av_bf) {
    int bid = blockIdx.x, tid = threadIdx.x;
    if (bid < DEGB) {
        __shared__ int hist[PSZ];  // 20 KiB
        int part = bid & 3;
        int b = (bid >> 2) & 3;
        int c = bid >> 4;
        const int lo = part * PSZ;
        for (int i = tid; i < PSZ; i += 256) hist[i] = 0;
        __syncthreads();
        const int4* dstp4 = (const int4*)(links + b * 2 * NED + NED + c * EPC);
        for (int q = tid; q < EPC / 4; q += 256) {
            int4 d = dstp4[q];
            if (d.x >= lo && d.x < lo + PSZ) atomicAdd(&hist[d.x - lo], 1);
            if (d.y >= lo && d.y < lo + PSZ) atomicAdd(&hist[d.y - lo], 1);
            if (d.z >= lo && d.z < lo + PSZ) atomicAdd(&hist[d.z - lo], 1);
            if (d.w >= lo && d.w < lo + PSZ) atomicAdd(&hist[d.w - lo], 1);
        }
        __syncthreads();
        int* out = dp + (size_t)(b * NCH + c) * NND + lo;
        for (int i = tid; i < PSZ; i += 256) out[i] = hist[i];
        return;
    }
    if (bid < DEGB + H0B) {
        __shared__ float sW[NFEAT * DD];
        __shared__ float sb[DD];
        __shared__ float sm[8], sr[8];
        for (int i = tid; i < NFEAT * DD; i += 256) sW[i] = Win[i];
        if (tid < DD) sb[tid] = bin[tid];
        if (tid < 8) {
            float inv_n = 1.f / (float)(NB * NND);
            float mean = stats[tid] * inv_n;
            float var = stats[8 + tid] * inv_n - mean * mean;
            var = fmaxf(var, 0.f);
            sm[tid] = mean;
            sr[tid] = 1.f / (sqrtf(var) + 1e-8f);
        }
        __syncthreads();
        for (int t = (bid - DEGB) * 256 + tid; t < NB * NND * 16; t += H0B * 256) {
            int bn = t >> 4;
            int j0 = (t & 15) << 3;
            const float* p = nodes + (size_t)bn * NFEAT;
            float acc[8];
#pragma unroll
            for (int jj = 0; jj < 8; ++jj) acc[jj] = sb[j0 + jj];
#pragma unroll
            for (int k = 0; k < 8; ++k) {
                float x = (p[k] - sm[k]) * sr[k];
#pragma unroll
                for (int jj = 0; jj < 8; ++jj) acc[jj] += x * sW[k * DD + j0 + jj];
            }
            uint4 r;
            r.x = ((unsigned)f2bf(fmaxf(acc[1], 0.f)) << 16) | (unsigned)f2bf(fmaxf(acc[0], 0.f));
            r.y = ((unsigned)f2bf(fmaxf(acc[3], 0.f)) << 16) | (unsigned)f2bf(fmaxf(acc[2], 0.f));
            r.z = ((unsigned)f2bf(fmaxf(acc[5], 0.f)) << 16) | (unsigned)f2bf(fmaxf(acc[4], 0.f));
            r.w = ((unsigned)f2bf(fmaxf(acc[7], 0.f)) << 16) | (unsigned)f2bf(fmaxf(acc[6], 0.f));
            *(uint4*)(h + (size_t)bn * DD + j0) = r;
        }
        return;
    }
    if (bid < DEGB + H0B + 313) {
        int g = (bid - DEGB - H0B) * 256 + tid;
        if (g < NB * NND) {
            int f = *flag;
            mc[g] = f ? (int)((const unsigned char*)m)[g] : ((const int*)m)[g];
        }
        return;
    }
    if (bid < DEGB + H0B + 313 + 3) {
        int mtx = bid - (DEGB + H0B + 313);
        const float* S0 = (mtx == 0) ? Wm1 : ((mtx == 1) ? Wm2 : Wp);
        const float* S1 = (mtx == 0) ? Ws1 : ((mtx == 1) ? Ws2 : (Wp + 128 * DD));
        unsigned short* D = (mtx == 0) ? B1t : ((mtx == 1) ? B2t : Bpt);
        for (int idx = tid; idx < 128 * 32; idx += 256) {
            int n = idx >> 5;
            int mm = idx & 31;
            short8 pk;
#pragma unroll
            for (int j = 0; j < 8; ++j) {
                int k = mm * 8 + j;
                float v = (k < 128) ? S0[k * DD + n] : S1[(k - 128) * DD + n];
                pk[j] = (short)f2bf(v);
            }
            int mst = mm ^ (n & 7);
            *(short8*)(D + n * 256 + mst * 8) = pk;
        }
        return;
    }
    // ad head (1 block)
    __shared__ float sn[NB * ADF];
    if (tid < ADF) {
        float mm = 0.f;
        for (int b = 0; b < NB; ++b) mm += ad[b * ADF + tid];
        mm *= 0.25f;
        float v = 0.f;
        for (int b = 0; b < NB; ++b) { float d = ad[b * ADF + tid] - mm; v += d * d; }
        v *= 0.25f;
        float r = 1.f / (sqrtf(v) + 1e-8f);
        for (int b = 0; b < NB; ++b) sn[b * ADF + tid] = (ad[b * ADF + tid] - mm) * r;
    }
    __syncthreads();
    for (int t = tid; t < NB * DD; t += 256) {
        int b = t >> 7, j = t & 127;
        float acc = bad[j];
#pragma unroll
        for (int k = 0; k < 8; ++k) acc += sn[b * ADF + k] * Wad[k * DD + j];
        float rl = fmaxf(acc, 0.f);
        av[t] = rl;
        av_bf[t] = f2bf(rl);
    }
}

// ---------------- 2-phase parallel scan (scanB folded into scanC) ----------------
__global__ __launch_bounds__(1024) void k_scanA(const int* __restrict__ dp, int* __restrict__ offs,
                                                int* __restrict__ segsum) {
    int b = blockIdx.x >> 5, seg = blockIdx.x & 31;
    int tid = threadIdx.x, lane = tid & 63, wv = tid >> 6;
    __shared__ int wsum[16], wexcl[16];
    int i = seg * SEGSZ + tid;
    int v = 0;
    if (tid < SEGSZ) {
#pragma unroll
        for (int q = 0; q < NCH; ++q) v += dp[(size_t)(b * NCH + q) * NND + i];
    }
    int x = v;
#pragma unroll
    for (int d = 1; d < 64; d <<= 1) {
        int t = __shfl_up(x, d, 64);
        if (lane >= d) x += t;
    }
    if (lane == 63) wsum[wv] = x;
    __syncthreads();
    if (wv == 0) {
        int s = (lane < 16) ? wsum[lane] : 0;
#pragma unroll
        for (int d = 1; d < 16; d <<= 1) {
            int t = __shfl_up(s, d, 64);
            if (lane >= d) s += t;
        }
        if (lane < 16) wexcl[lane] = s - wsum[lane];
    }
    __syncthreads();
    int excl = wexcl[wv] + (x - v);
    if (tid < SEGSZ) offs[b * (NND + 1) + i] = excl;   // local exclusive (temp)
    if (tid == SEGSZ - 1) segsum[blockIdx.x] = excl + v;
}

// scanC: every block redundantly computes its segment base from raw segsums.
__global__ __launch_bounds__(1024) void k_scanC(int* __restrict__ dp, int* __restrict__ offs,
                                                const int* __restrict__ segsum) {
    int b = blockIdx.x >> 5, seg = blockIdx.x & 31;
    int tid = threadIdx.x;
    int base = 0;
    for (int s = 0; s < NSEG; ++s) {
        int t = segsum[b * NSEG + s];
        if (s < seg) base += t;
    }
    if (seg == NSEG - 1 && tid == 0)
        offs[b * (NND + 1) + NND] = base + segsum[b * NSEG + NSEG - 1];
    if (tid >= SEGSZ) return;
    int i = seg * SEGSZ + tid;
    int excl = base + offs[b * (NND + 1) + i];
    offs[b * (NND + 1) + i] = excl;
    int run = excl;
#pragma unroll
    for (int q = 0; q < NCH; ++q) {
        size_t a = (size_t)(b * NCH + q) * NND + i;
        int p = dp[a];
        dp[a] = run;
        run += p;
    }
}

// ---------------- CSR fill via LDS cursors ----------------
__global__ __launch_bounds__(256) void k_fill(const int* __restrict__ links, const int* __restrict__ dp,
                                              int* __restrict__ csr) {
    __shared__ int cur[PSZ];  // 20 KiB
    int bid = blockIdx.x, tid = threadIdx.x;
    int part = bid & 3;
    int b = (bid >> 2) & 3;
    int c = bid >> 4;
    const int lo = part * PSZ;
    const int* cstart = dp + (size_t)(b * NCH + c) * NND + lo;
    for (int i = tid; i < PSZ; i += 256) cur[i] = cstart[i];
    __syncthreads();
    const int4* dstp4 = (const int4*)(links + b * 2 * NED + NED + c * EPC);
    const int* srcp = links + b * 2 * NED + c * EPC;
    int* cs = csr + (size_t)b * NED;
    for (int q = tid; q < EPC / 4; q += 256) {
        int4 d = dstp4[q];
        int e = q * 4;
        if (d.x >= lo && d.x < lo + PSZ) { int pos = atomicAdd(&cur[d.x - lo], 1); cs[pos] = srcp[e]; }
        if (d.y >= lo && d.y < lo + PSZ) { int pos = atomicAdd(&cur[d.y - lo], 1); cs[pos] = srcp[e + 1]; }
        if (d.z >= lo && d.z < lo + PSZ) { int pos = atomicAdd(&cur[d.z - lo], 1); cs[pos] = srcp[e + 2]; }
        if (d.w >= lo && d.w < lo + PSZ) { int pos = atomicAdd(&cur[d.w - lo], 1); cs[pos] = srcp[e + 3]; }
    }
}

// ---------------- agg[n] = sum_{src->n} h[src]  (wave/node + XCD-batch affinity, pipelined) ----------------
__global__ __launch_bounds__(256) void k_gather(const unsigned short* __restrict__ h, const int* __restrict__ offs,
                                                const int* __restrict__ csr, unsigned short* __restrict__ agg) {
    int bid = blockIdx.x;
    int xcd = bid & 7;
    int b = xcd >> 1;
    int sub = (bid >> 3) * 2 + (xcd & 1);
    int n = sub * 4 + (threadIdx.x >> 6);
    int lane = threadIdx.x & 63;
    if (n >= NND) return;
    int wid = b * NND + n;
    int off0 = offs[b * (NND + 1) + n];
    int off1 = offs[b * (NND + 1) + n + 1];
    int g = lane >> 4, c = lane & 15;
    float acc[8] = {0.f,0.f,0.f,0.f,0.f,0.f,0.f,0.f};
    const uint4* hb = (const uint4*)(h + (size_t)b * NND * DD);
    const int* cs = csr + (size_t)b * NED;
    for (int base = off0; base < off1; base += 64) {
        int cnt = min(64, off1 - base);
        int idx = (lane < cnt) ? cs[base + lane] : 0;
        int full = cnt >> 2;
        if (full > 0) {
            int srcn = __shfl(idx, g, 64);
            uint4 v = hb[srcn * 16 + c];
            for (int j = 1; j < full; ++j) {
                int srcn2 = __shfl(idx, j * 4 + g, 64);
                uint4 v2 = hb[srcn2 * 16 + c];
                float f[8];
                unpack8(v, f);
#pragma unroll
                for (int k = 0; k < 8; ++k) acc[k] += f[k];
                v = v2;
            }
            float f[8];
            unpack8(v, f);
#pragma unroll
            for (int k = 0; k < 8; ++k) acc[k] += f[k];
        }
        int q = full * 4 + g;
        int srcn = __shfl(idx, q, 64);
        if (q < cnt) {
            uint4 v = hb[srcn * 16 + c];
            float f[8];
            unpack8(v, f);
#pragma unroll
            for (int k = 0; k < 8; ++k) acc[k] += f[k];
        }
    }
#pragma unroll
    for (int k = 0; k < 8; ++k) {
        acc[k] += __shfl_xor(acc[k], 16, 64);
        acc[k] += __shfl_xor(acc[k], 32, 64);
    }
    if (lane < 16) {
        uint4 r;
        r.x = ((unsigned)f2bf(acc[1]) << 16) | (unsigned)f2bf(acc[0]);
        r.y = ((unsigned)f2bf(acc[3]) << 16) | (unsigned)f2bf(acc[2]);
        r.z = ((unsigned)f2bf(acc[5]) << 16) | (unsigned)f2bf(acc[4]);
        r.w = ((unsigned)f2bf(acc[7]) << 16) | (unsigned)f2bf(acc[6]);
        ((uint4*)(agg + (size_t)wid * DD))[c] = r;
    }
}

// ---------------- MFMA: h_new = relu([agg,h] @ Bt + bias) -> bf16 (256 rows/block) ----------------
__global__ __launch_bounds__(256) void k_mp_mfma(const unsigned short* __restrict__ Xa,
                                                 const unsigned short* __restrict__ Xh,
                                                 const unsigned short* __restrict__ Bt,
                                                 const float* __restrict__ bias,
                                                 unsigned short* __restrict__ Out) {
    __shared__ unsigned short sB[128 * 256];
    {
        const uint4* s4 = (const uint4*)Bt;
        uint4* d4 = (uint4*)sB;
        for (int i = threadIdx.x; i < 4096; i += 256) d4[i] = s4[i];
    }
    __syncthreads();
    int wave = threadIdx.x >> 6, lane = threadIdx.x & 63;
    int row0 = blockIdx.x * 256 + wave * 64;
    int arow = lane & 15, kgrp = lane >> 4;
    f32x4 acc[4][8];
#pragma unroll
    for (int s = 0; s < 4; ++s)
#pragma unroll
        for (int c = 0; c < 8; ++c) acc[s][c] = (f32x4){0.f, 0.f, 0.f, 0.f};
    const unsigned short* aptr[4];
    const unsigned short* hptr[4];
#pragma unroll
    for (int s = 0; s < 4; ++s) {
        int r = row0 + s * 16 + arow;
        int rr = (r < MROWS) ? r : (MROWS - 1);
        aptr[s] = Xa + (size_t)rr * DD + kgrp * 8;
        hptr[s] = Xh + (size_t)rr * DD + kgrp * 8;
    }
#pragma unroll
    for (int ks = 0; ks < 8; ++ks) {
        short8 a[4];
#pragma unroll
        for (int s = 0; s < 4; ++s)
            a[s] = (ks < 4) ? *(const short8*)(aptr[s] + ks * 32)
                            : *(const short8*)(hptr[s] + (ks - 4) * 32);
#pragma unroll
        for (int c = 0; c < 8; ++c) {
            int n = c * 16 + arow;
            int mst = (ks * 4 + kgrp) ^ (n & 7);
            short8 bfr = *(const short8*)(sB + n * 256 + mst * 8);
#pragma unroll
            for (int s = 0; s < 4; ++s)
                acc[s][c] = __builtin_amdgcn_mfma_f32_16x16x32_bf16(a[s], bfr, acc[s][c], 0, 0, 0);
        }
    }
    float bcol[8];
#pragma unroll
    for (int c = 0; c < 8; ++c) bcol[c] = bias[c * 16 + arow];
#pragma unroll
    for (int s = 0; s < 4; ++s) {
#pragma unroll
        for (int j = 0; j < 4; ++j) {
            int r = row0 + s * 16 + kgrp * 4 + j;
            if (r < MROWS) {
                unsigned short* orow = Out + (size_t)r * DD;
#pragma unroll
                for (int c = 0; c < 8; ++c) {
                    float v = fmaxf(acc[s][c][j] + bcol[c], 0.f);
                    orow[c * 16 + arow] = f2bf(v);
                }
            }
        }
    }
}

// ---------------- MFMA pair+dot: logits + fused batch-max (256 rows/block) ----------------
__global__ __launch_bounds__(256) void k_pair_mfma(const unsigned short* __restrict__ Xh,
                                                   const unsigned short* __restrict__ Abf,
                                                   const unsigned short* __restrict__ Bt,
                                                   const float* __restrict__ bp,
                                                   const float* __restrict__ wout,
                                                   const int* __restrict__ mc,
                                                   float* __restrict__ logits,
                                                   unsigned* __restrict__ mtrans) {
    __shared__ unsigned short sB[128 * 256];
    __shared__ unsigned smax[NB];
    {
        const uint4* s4 = (const uint4*)Bt;
        uint4* d4 = (uint4*)sB;
        for (int i = threadIdx.x; i < 4096; i += 256) d4[i] = s4[i];
        if (threadIdx.x < NB) smax[threadIdx.x] = 0u;
    }
    __syncthreads();
    int wave = threadIdx.x >> 6, lane = threadIdx.x & 63;
    int row0 = blockIdx.x * 256 + wave * 64;
    int arow = lane & 15, kgrp = lane >> 4;
    f32x4 acc[4][8];
#pragma unroll
    for (int s = 0; s < 4; ++s)
#pragma unroll
        for (int c = 0; c < 8; ++c) acc[s][c] = (f32x4){0.f, 0.f, 0.f, 0.f};
    const unsigned short* hptr[4];
    const unsigned short* aptr[4];
#pragma unroll
    for (int s = 0; s < 4; ++s) {
        int r = row0 + s * 16 + arow;
        int rr = (r < MROWS) ? r : (MROWS - 1);
        hptr[s] = Xh + (size_t)rr * DD + kgrp * 8;
        aptr[s] = Abf + (size_t)(rr / NND) * DD + kgrp * 8;
    }
#pragma unroll
    for (int ks = 0; ks < 8; ++ks) {
        short8 a[4];
#pragma unroll
        for (int s = 0; s < 4; ++s)
            a[s] = (ks < 4) ? *(const short8*)(hptr[s] + ks * 32)
                            : *(const short8*)(aptr[s] + (ks - 4) * 32);
#pragma unroll
        for (int c = 0; c < 8; ++c) {
            int n = c * 16 + arow;
            int mst = (ks * 4 + kgrp) ^ (n & 7);
            short8 bfr = *(const short8*)(sB + n * 256 + mst * 8);
#pragma unroll
            for (int s = 0; s < 4; ++s)
                acc[s][c] = __builtin_amdgcn_mfma_f32_16x16x32_bf16(a[s], bfr, acc[s][c], 0, 0, 0);
        }
    }
    float bpc[8], wc[8];
#pragma unroll
    for (int c = 0; c < 8; ++c) {
        int col = c * 16 + arow;
        bpc[c] = bp[col];
        wc[c] = wout[col];
    }
#pragma unroll
    for (int s = 0; s < 4; ++s) {
#pragma unroll
        for (int j = 0; j < 4; ++j) {
            float v = 0.f;
#pragma unroll
            for (int c = 0; c < 8; ++c)
                v += fmaxf(acc[s][c][j] + bpc[c], 0.f) * wc[c];
            v += __shfl_xor(v, 1, 64);
            v += __shfl_xor(v, 2, 64);
            v += __shfl_xor(v, 4, 64);
            v += __shfl_xor(v, 8, 64);
            int r = row0 + s * 16 + kgrp * 4 + j;
            if (arow == 0 && r < MROWS) {
                float lv = mc[r] ? v : NEGINF;
                logits[r] = lv;
                atomicMax(&smax[r / NND], ftrans(lv));
            }
        }
    }
    __syncthreads();
    if (threadIdx.x < NB && smax[threadIdx.x] != 0u)
        atomicMax(mtrans + threadIdx.x, smax[threadIdx.x]);
}

// ---------------- fused sumexp + context ----------------
#define CTX_CH 128
#define CTX_RPB ((NND + CTX_CH - 1) / CTX_CH)
__global__ __launch_bounds__(256) void k_ctxsum(const float* __restrict__ logits, const unsigned short* __restrict__ h,
                                                const unsigned* __restrict__ mtrans, float* S, float* ctx) {
    int b = blockIdx.x >> 7, chunk = blockIdx.x & (CTX_CH - 1);
    int rowstart = chunk * CTX_RPB;
    int rowend = min(rowstart + CTX_RPB, NND);
    int wave = threadIdx.x >> 6, lane = threadIdx.x & 63;
    int g = lane >> 4, c = lane & 15;
    float m = finv(mtrans[b]);
    float acc[8] = {0.f,0.f,0.f,0.f,0.f,0.f,0.f,0.f};
    float ws = 0.f;
    const uint4* hb = (const uint4*)(h + (size_t)b * NND * DD);
    const float* lg = logits + b * NND;
    for (int r0 = rowstart + wave * 4; r0 < rowend; r0 += 16) {
        int row = r0 + g;
        if (row < rowend) {
            float w = expf(lg[row] - m);
            ws += w;
            uint4 v = hb[row * 16 + c];
            float f[8];
            unpack8(v, f);
#pragma unroll
            for (int k = 0; k < 8; ++k) acc[k] += w * f[k];
        }
    }
#pragma unroll
    for (int k = 0; k < 8; ++k) {
        acc[k] += __shfl_xor(acc[k], 16, 64);
        acc[k] += __shfl_xor(acc[k], 32, 64);
    }
    ws += __shfl_xor(ws, 16, 64);
    ws += __shfl_xor(ws, 32, 64);
    __shared__ float sctx[4][128];
    __shared__ float sws[4];
    if (lane < 16) {
#pragma unroll
        for (int k = 0; k < 8; ++k) sctx[wave][lane * 8 + k] = acc[k];
    }
    if (lane == 0) sws[wave] = ws;
    __syncthreads();
    int tid = threadIdx.x;
    if (tid < 128) {
        float t = sctx[0][tid] + sctx[1][tid] + sctx[2][tid] + sctx[3][tid];
        atomicAdd(ctx + b * DD + tid, t);
    }
    if (tid == 0) atomicAdd(S + b, sws[0] + sws[1] + sws[2] + sws[3]);
}

// ---------------- log_probs out + value head (block 313) ----------------
__global__ __launch_bounds__(256) void k_final(const float* __restrict__ logits, const unsigned* __restrict__ mtrans,
                                               const float* __restrict__ S, const float* __restrict__ ctx,
                                               const float* __restrict__ av, const float* __restrict__ Wv,
                                               const float* __restrict__ bv, const float* __restrict__ wvo,
                                               float* __restrict__ out) {
    int tid = threadIdx.x;
    if (blockIdx.x == 313) {
        __shared__ float red[512];
#pragma unroll
        for (int half = 0; half < 2; ++half) {
            for (int t = tid; t < 2 * 256; t += 256) {
                int b = half * 2 + (t >> 7), j = t & 127;
                float sb = S[b];
                float s1 = 0.f, s2 = 0.f;
                for (int k = 0; k < 128; ++k) s1 += ctx[b * DD + k] * Wv[k * DD + j];
                for (int k = 0; k < 128; ++k) s2 += av[b * DD + k] * Wv[(128 + k) * DD + j];
                float acc = bv[j] + s1 / sb + s2;
                red[t] = fmaxf(acc, 0.f) * wvo[j];
            }
            __syncthreads();
            int j = tid & 127;
            for (int off = 64; off; off >>= 1) {
                if (j < off) {
                    red[tid] += red[tid + off];
                    red[tid + 256] += red[tid + 256 + off];
                }
                __syncthreads();
            }
            if (tid < 2) out[NB * NND + half * 2 + tid] = red[tid * 128];
            __syncthreads();
        }
        return;
    }
    int g = blockIdx.x * 256 + tid;
    if (g >= NB * NND) return;
    int b = g / NND;
    out[g] = logits[g] - finv(mtrans[b]) - logf(S[b]);
}

extern "C" void kernel_launch(void* const* d_in, const int* in_sizes, int n_in,
                              void* d_out, int out_size, void* d_ws, size_t ws_size,
                              hipStream_t stream) {
    const float* nodes = (const float*)d_in[0];
    const int* links = (const int*)d_in[1];
    const void* mask = d_in[2];
    const float* ad = (const float*)d_in[3];
    const float* Win = (const float*)d_in[4];
    const float* bin = (const float*)d_in[5];
    const float* Wm1 = (const float*)d_in[6];
    const float* Ws1 = (const float*)d_in[7];
    const float* b1 = (const float*)d_in[8];
    const float* Wm2 = (const float*)d_in[9];
    const float* Ws2 = (const float*)d_in[10];
    const float* b2 = (const float*)d_in[11];
    const float* Wad = (const float*)d_in[12];
    const float* bad = (const float*)d_in[13];
    const float* Wp = (const float*)d_in[14];
    const float* bp = (const float*)d_in[15];
    const float* wout = (const float*)d_in[16];
    const float* Wv = (const float*)d_in[17];
    const float* bv = (const float*)d_in[18];
    const float* wvo = (const float*)d_in[19];
    float* out = (float*)d_out;

    unsigned short* hA = (unsigned short*)d_ws;     // h0/h1/h2
    unsigned short* hB = hA + 10240000;             // agg
    unsigned short* B1t = hB + 10240000;
    unsigned short* B2t = B1t + 32768;
    unsigned short* Bpt = B2t + 32768;
    unsigned short* a_bf = Bpt + 32768;
    float* logits = (float*)(a_bf + 512);
    float* stats = logits + 80000;
    float* a_vec = stats + 64;
    float* Sexp = a_vec + 512;
    float* ctxb = Sexp + 64;
    unsigned* mtrans = (unsigned*)(ctxb + 512);
    int* dp = (int*)(mtrans + 64);                  // NB*NCH*NND = 2,560,000
    int* offs = dp + NB * NCH * NND;                // 80,064
    int* csr = offs + 80064;                        // 1,280,000
    int* mc = csr + 1280000;                        // 80,000
    int* flag = mc + 80000;                         // 64
    int* segsum = flag + 64;                        // 128

    k_init<<<3, 256, 0, stream>>>(stats, mtrans, Sexp, ctxb, (const unsigned char*)mask, flag);
    k_stats<<<256, 256, 0, stream>>>(nodes, stats);
    k_setup<<<DEGB + H0B + 313 + 3 + 1, 256, 0, stream>>>(links, dp, nodes, stats, Win, bin, hA,
                                                          mask, flag, mc,
                                                          Wm1, Ws1, Wm2, Ws2, Wp, B1t, B2t, Bpt,
                                                          ad, Wad, bad, a_vec, a_bf);
    k_scanA<<<NB * NSEG, 1024, 0, stream>>>(dp, offs, segsum);
    k_scanC<<<NB * NSEG, 1024, 0, stream>>>(dp, offs, segsum);
    k_fill<<<DEGB, 256, 0, stream>>>(links, dp, csr);

    k_gather<<<20000, 256, 0, stream>>>(hA, offs, csr, hB);
    k_mp_mfma<<<313, 256, 0, stream>>>(hB, hA, B1t, b1, hA);
    k_gather<<<20000, 256, 0, stream>>>(hA, offs, csr, hB);
    k_mp_mfma<<<313, 256, 0, stream>>>(hB, hA, B2t, b2, hA);

    k_pair_mfma<<<313, 256, 0, stream>>>(hA, a_bf, Bpt, bp, wout, mc, logits, mtrans);
    k_ctxsum<<<NB * CTX_CH, 256, 0, stream>>>(logits, hA, mtrans, Sexp, ctxb);
    k_final<<<314, 256, 0, stream>>>(logits, mtrans, Sexp, ctxb, a_vec, Wv, bv, wvo, out);
}

// Round 17
// 231.063 us; speedup vs baseline: 1.1499x; 1.0302x over previous
//
#include <hip/hip_runtime.h>
#include <hip/hip_bf16.h>
#include <math.h>

#define NND 20000
#define NED 320000
#define NB 4
#define NFEAT 8
#define ADF 8
#define DD 128
#define MROWS (NB * NND)
#define NEGINF -1000000000.0f
#define NCH 32
#define EPC (NED / NCH)     // 10000 edges per chunk
#define NPART 4
#define PSZ (NND / NPART)   // 5000 nodes per part (20 KiB LDS)
#define DEGB (NB * NPART * NCH)  // 512 blocks
#define NSEG 32
#define SEGSZ (NND / NSEG)  // 625 nodes per scan segment
#define H0B 1024            // h0 blocks inside k_setup
#define STATB 256           // stats-partial blocks inside k_init

typedef __attribute__((ext_vector_type(8))) short short8;
typedef __attribute__((ext_vector_type(4))) float f32x4;

__device__ __forceinline__ unsigned ftrans(float f) {
    unsigned u = __float_as_uint(f);
    return (u & 0x80000000u) ? ~u : (u | 0x80000000u);
}
__device__ __forceinline__ float finv(unsigned t) {
    unsigned u = (t & 0x80000000u) ? (t & 0x7fffffffu) : ~t;
    return __uint_as_float(u);
}
__device__ __forceinline__ unsigned short f2bf(float f) {  // RNE, finite inputs
    unsigned u = __float_as_uint(f);
    unsigned r = u + 0x7fffu + ((u >> 16) & 1u);
    return (unsigned short)(r >> 16);
}
__device__ __forceinline__ float bf2f(unsigned short b) {
    return __uint_as_float(((unsigned)b) << 16);
}
__device__ __forceinline__ void unpack8(uint4 v, float* f) {
    f[0] = __uint_as_float(v.x << 16); f[1] = __uint_as_float(v.x & 0xffff0000u);
    f[2] = __uint_as_float(v.y << 16); f[3] = __uint_as_float(v.y & 0xffff0000u);
    f[4] = __uint_as_float(v.z << 16); f[5] = __uint_as_float(v.z & 0xffff0000u);
    f[6] = __uint_as_float(v.w << 16); f[7] = __uint_as_float(v.w & 0xffff0000u);
}

// ---------------- init: scratch zeroing + mask flag + stats block-partials ----------------
// bid 0,1: zero scratch; bid 2: mask dtype flag; bid [3, 3+STATB): per-block
// stats partials -> pstats[blk][16] (plain stores, race-free, no zeroing needed).
__global__ __launch_bounds__(256) void k_init(unsigned* mtrans, float* S, float* ctx,
                                              const unsigned char* __restrict__ m, int* flag,
                                              const float* __restrict__ nodes, float* __restrict__ pstats) {
    int bid = blockIdx.x, tid = threadIdx.x;
    if (bid == 2) {
        __shared__ int any;
        if (tid == 0) any = 0;
        __syncthreads();
        int found = 0;
        for (int p = tid; p < 4096; p += 256)
            if ((p & 3) && m[p]) found = 1;
        if (found) atomicOr(&any, 1);
        __syncthreads();
        if (tid == 0) *flag = any;
        return;
    }
    if (bid < 2) {
        int i = bid * 256 + tid;
        if (i < NB) { mtrans[i] = 0u; S[i] = 0.f; }
        if (i < NB * DD) ctx[i] = 0.f;
        return;
    }
    // stats partials
    int blk = bid - 3;
    int gid = blk * 256 + tid;
    float s[8] = {0.f,0.f,0.f,0.f,0.f,0.f,0.f,0.f};
    float q[8] = {0.f,0.f,0.f,0.f,0.f,0.f,0.f,0.f};
    for (int r = gid; r < NB * NND; r += STATB * 256) {
        const float* p = nodes + (size_t)r * NFEAT;
#pragma unroll
        for (int k = 0; k < 8; ++k) { float v = p[k]; s[k] += v; q[k] += v * v; }
    }
#pragma unroll
    for (int k = 0; k < 8; ++k) {
        for (int off = 32; off; off >>= 1) {
            s[k] += __shfl_xor(s[k], off, 64);
            q[k] += __shfl_xor(q[k], off, 64);
        }
    }
    __shared__ float ls[4][16];
    int w = tid >> 6, lane = tid & 63;
    if (lane == 0) {
#pragma unroll
        for (int k = 0; k < 8; ++k) { ls[w][k] = s[k]; ls[w][8 + k] = q[k]; }
    }
    __syncthreads();
    if (tid < 16)
        pstats[blk * 16 + tid] = ls[0][tid] + ls[1][tid] + ls[2][tid] + ls[3][tid];
}

// ---------------- fused setup: deg-partials + h0 + maskc + prep + ad ----------------
// blocks [0,DEGB): deg histograms (part=bid&3, b=(bid>>2)&3, c=bid>>4);
// [DEGB,DEGB+H0B): h0 (reduces pstats itself); then maskc(313), prep(3), ad(1).
__global__ __launch_bounds__(256) void k_setup(const int* __restrict__ links, int* __restrict__ dp,
                                               const float* __restrict__ nodes, const float* __restrict__ pstats,
                                               const float* __restrict__ Win, const float* __restrict__ bin,
                                               unsigned short* __restrict__ h,
                                               const void* __restrict__ m, const int* __restrict__ flag,
                                               int* __restrict__ mc,
                                               const float* __restrict__ Wm1, const float* __restrict__ Ws1,
                                               const float* __restrict__ Wm2, const float* __restrict__ Ws2,
                                               const float* __restrict__ Wp,
                                               unsigned short* __restrict__ B1t, unsigned short* __restrict__ B2t,
                                               unsigned short* __restrict__ Bpt,
                                               const float* __restrict__ ad, const float* __restrict__ Wad,
                                               const float* __restrict__ bad, float* __restrict__ av,
                                               unsigned short* __restrict__ av_bf) {
    int bid = blockIdx.x, tid = threadIdx.x;
    if (bid < DEGB) {
        __shared__ int hist[PSZ];  // 20 KiB
        int part = bid & 3;
        int b = (bid >> 2) & 3;
        int c = bid >> 4;
        const int lo = part * PSZ;
        for (int i = tid; i < PSZ; i += 256) hist[i] = 0;
        __syncthreads();
        const int4* dstp4 = (const int4*)(links + b * 2 * NED + NED + c * EPC);
        for (int q = tid; q < EPC / 4; q += 256) {
            int4 d = dstp4[q];
            if (d.x >= lo && d.x < lo + PSZ) atomicAdd(&hist[d.x - lo], 1);
            if (d.y >= lo && d.y < lo + PSZ) atomicAdd(&hist[d.y - lo], 1);
            if (d.z >= lo && d.z < lo + PSZ) atomicAdd(&hist[d.z - lo], 1);
            if (d.w >= lo && d.w < lo + PSZ) atomicAdd(&hist[d.w - lo], 1);
        }
        __syncthreads();
        int* out = dp + (size_t)(b * NCH + c) * NND + lo;
        for (int i = tid; i < PSZ; i += 256) out[i] = hist[i];
        return;
    }
    if (bid < DEGB + H0B) {
        __shared__ float sW[NFEAT * DD];
        __shared__ float sb[DD];
        __shared__ float sm[8], sr[8];
        __shared__ float ls[4][16];
        // reduce pstats (256 x 16) -> 16 totals
        {
            float part[16];
#pragma unroll
            for (int k = 0; k < 16; ++k) part[k] = pstats[tid * 16 + k];
#pragma unroll
            for (int k = 0; k < 16; ++k) {
                for (int off = 32; off; off >>= 1)
                    part[k] += __shfl_xor(part[k], off, 64);
            }
            int w = tid >> 6, lane = tid & 63;
            if (lane == 0) {
#pragma unroll
                for (int k = 0; k < 16; ++k) ls[w][k] = part[k];
            }
        }
        for (int i = tid; i < NFEAT * DD; i += 256) sW[i] = Win[i];
        if (tid < DD) sb[tid] = bin[tid];
        __syncthreads();
        if (tid < 8) {
            float tot_s = ls[0][tid] + ls[1][tid] + ls[2][tid] + ls[3][tid];
            float tot_q = ls[0][8 + tid] + ls[1][8 + tid] + ls[2][8 + tid] + ls[3][8 + tid];
            float inv_n = 1.f / (float)(NB * NND);
            float mean = tot_s * inv_n;
            float var = tot_q * inv_n - mean * mean;
            var = fmaxf(var, 0.f);
            sm[tid] = mean;
            sr[tid] = 1.f / (sqrtf(var) + 1e-8f);
        }
        __syncthreads();
        for (int t = (bid - DEGB) * 256 + tid; t < NB * NND * 16; t += H0B * 256) {
            int bn = t >> 4;
            int j0 = (t & 15) << 3;
            const float* p = nodes + (size_t)bn * NFEAT;
            float acc[8];
#pragma unroll
            for (int jj = 0; jj < 8; ++jj) acc[jj] = sb[j0 + jj];
#pragma unroll
            for (int k = 0; k < 8; ++k) {
                float x = (p[k] - sm[k]) * sr[k];
#pragma unroll
                for (int jj = 0; jj < 8; ++jj) acc[jj] += x * sW[k * DD + j0 + jj];
            }
            uint4 r;
            r.x = ((unsigned)f2bf(fmaxf(acc[1], 0.f)) << 16) | (unsigned)f2bf(fmaxf(acc[0], 0.f));
            r.y = ((unsigned)f2bf(fmaxf(acc[3], 0.f)) << 16) | (unsigned)f2bf(fmaxf(acc[2], 0.f));
            r.z = ((unsigned)f2bf(fmaxf(acc[5], 0.f)) << 16) | (unsigned)f2bf(fmaxf(acc[4], 0.f));
            r.w = ((unsigned)f2bf(fmaxf(acc[7], 0.f)) << 16) | (unsigned)f2bf(fmaxf(acc[6], 0.f));
            *(uint4*)(h + (size_t)bn * DD + j0) = r;
        }
        return;
    }
    if (bid < DEGB + H0B + 313) {
        int g = (bid - DEGB - H0B) * 256 + tid;
        if (g < NB * NND) {
            int f = *flag;
            mc[g] = f ? (int)((const unsigned char*)m)[g] : ((const int*)m)[g];
        }
        return;
    }
    if (bid < DEGB + H0B + 313 + 3) {
        int mtx = bid - (DEGB + H0B + 313);
        const float* S0 = (mtx == 0) ? Wm1 : ((mtx == 1) ? Wm2 : Wp);
        const float* S1 = (mtx == 0) ? Ws1 : ((mtx == 1) ? Ws2 : (Wp + 128 * DD));
        unsigned short* D = (mtx == 0) ? B1t : ((mtx == 1) ? B2t : Bpt);
        for (int idx = tid; idx < 128 * 32; idx += 256) {
            int n = idx >> 5;
            int mm = idx & 31;
            short8 pk;
#pragma unroll
            for (int j = 0; j < 8; ++j) {
                int k = mm * 8 + j;
                float v = (k < 128) ? S0[k * DD + n] : S1[(k - 128) * DD + n];
                pk[j] = (short)f2bf(v);
            }
            int mst = mm ^ (n & 7);
            *(short8*)(D + n * 256 + mst * 8) = pk;
        }
        return;
    }
    // ad head (1 block)
    __shared__ float sn[NB * ADF];
    if (tid < ADF) {
        float mm = 0.f;
        for (int b = 0; b < NB; ++b) mm += ad[b * ADF + tid];
        mm *= 0.25f;
        float v = 0.f;
        for (int b = 0; b < NB; ++b) { float d = ad[b * ADF + tid] - mm; v += d * d; }
        v *= 0.25f;
        float r = 1.f / (sqrtf(v) + 1e-8f);
        for (int b = 0; b < NB; ++b) sn[b * ADF + tid] = (ad[b * ADF + tid] - mm) * r;
    }
    __syncthreads();
    for (int t = tid; t < NB * DD; t += 256) {
        int b = t >> 7, j = t & 127;
        float acc = bad[j];
#pragma unroll
        for (int k = 0; k < 8; ++k) acc += sn[b * ADF + k] * Wad[k * DD + j];
        float rl = fmaxf(acc, 0.f);
        av[t] = rl;
        av_bf[t] = f2bf(rl);
    }
}

// ---------------- 2-phase parallel scan ----------------
__global__ __launch_bounds__(1024) void k_scanA(const int* __restrict__ dp, int* __restrict__ offs,
                                                int* __restrict__ segsum) {
    int b = blockIdx.x >> 5, seg = blockIdx.x & 31;
    int tid = threadIdx.x, lane = tid & 63, wv = tid >> 6;
    __shared__ int wsum[16], wexcl[16];
    int i = seg * SEGSZ + tid;
    int v = 0;
    if (tid < SEGSZ) {
#pragma unroll
        for (int q = 0; q < NCH; ++q) v += dp[(size_t)(b * NCH + q) * NND + i];
    }
    int x = v;
#pragma unroll
    for (int d = 1; d < 64; d <<= 1) {
        int t = __shfl_up(x, d, 64);
        if (lane >= d) x += t;
    }
    if (lane == 63) wsum[wv] = x;
    __syncthreads();
    if (wv == 0) {
        int s = (lane < 16) ? wsum[lane] : 0;
#pragma unroll
        for (int d = 1; d < 16; d <<= 1) {
            int t = __shfl_up(s, d, 64);
            if (lane >= d) s += t;
        }
        if (lane < 16) wexcl[lane] = s - wsum[lane];
    }
    __syncthreads();
    int excl = wexcl[wv] + (x - v);
    if (tid < SEGSZ) offs[b * (NND + 1) + i] = excl;
    if (tid == SEGSZ - 1) segsum[blockIdx.x] = excl + v;
}

__global__ __launch_bounds__(1024) void k_scanC(int* __restrict__ dp, int* __restrict__ offs,
                                                const int* __restrict__ segsum) {
    int b = blockIdx.x >> 5, seg = blockIdx.x & 31;
    int tid = threadIdx.x;
    int base = 0;
    for (int s = 0; s < NSEG; ++s) {
        int t = segsum[b * NSEG + s];
        if (s < seg) base += t;
    }
    if (seg == NSEG - 1 && tid == 0)
        offs[b * (NND + 1) + NND] = base + segsum[b * NSEG + NSEG - 1];
    if (tid >= SEGSZ) return;
    int i = seg * SEGSZ + tid;
    int excl = base + offs[b * (NND + 1) + i];
    offs[b * (NND + 1) + i] = excl;
    int run = excl;
#pragma unroll
    for (int q = 0; q < NCH; ++q) {
        size_t a = (size_t)(b * NCH + q) * NND + i;
        int p = dp[a];
        dp[a] = run;
        run += p;
    }
}

// ---------------- CSR fill via LDS cursors ----------------
__global__ __launch_bounds__(256) void k_fill(const int* __restrict__ links, const int* __restrict__ dp,
                                              int* __restrict__ csr) {
    __shared__ int cur[PSZ];  // 20 KiB
    int bid = blockIdx.x, tid = threadIdx.x;
    int part = bid & 3;
    int b = (bid >> 2) & 3;
    int c = bid >> 4;
    const int lo = part * PSZ;
    const int* cstart = dp + (size_t)(b * NCH + c) * NND + lo;
    for (int i = tid; i < PSZ; i += 256) cur[i] = cstart[i];
    __syncthreads();
    const int4* dstp4 = (const int4*)(links + b * 2 * NED + NED + c * EPC);
    const int* srcp = links + b * 2 * NED + c * EPC;
    int* cs = csr + (size_t)b * NED;
    for (int q = tid; q < EPC / 4; q += 256) {
        int4 d = dstp4[q];
        int e = q * 4;
        if (d.x >= lo && d.x < lo + PSZ) { int pos = atomicAdd(&cur[d.x - lo], 1); cs[pos] = srcp[e]; }
        if (d.y >= lo && d.y < lo + PSZ) { int pos = atomicAdd(&cur[d.y - lo], 1); cs[pos] = srcp[e + 1]; }
        if (d.z >= lo && d.z < lo + PSZ) { int pos = atomicAdd(&cur[d.z - lo], 1); cs[pos] = srcp[e + 2]; }
        if (d.w >= lo && d.w < lo + PSZ) { int pos = atomicAdd(&cur[d.w - lo], 1); cs[pos] = srcp[e + 3]; }
    }
}

// ---------------- agg[n] = sum_{src->n} h[src]  (wave/node + XCD-batch affinity, pipelined) ----------------
__global__ __launch_bounds__(256) void k_gather(const unsigned short* __restrict__ h, const int* __restrict__ offs,
                                                const int* __restrict__ csr, unsigned short* __restrict__ agg) {
    int bid = blockIdx.x;
    int xcd = bid & 7;
    int b = xcd >> 1;
    int sub = (bid >> 3) * 2 + (xcd & 1);
    int n = sub * 4 + (threadIdx.x >> 6);
    int lane = threadIdx.x & 63;
    if (n >= NND) return;
    int wid = b * NND + n;
    int off0 = offs[b * (NND + 1) + n];
    int off1 = offs[b * (NND + 1) + n + 1];
    int g = lane >> 4, c = lane & 15;
    float acc[8] = {0.f,0.f,0.f,0.f,0.f,0.f,0.f,0.f};
    const uint4* hb = (const uint4*)(h + (size_t)b * NND * DD);
    const int* cs = csr + (size_t)b * NED;
    for (int base = off0; base < off1; base += 64) {
        int cnt = min(64, off1 - base);
        int idx = (lane < cnt) ? cs[base + lane] : 0;
        int full = cnt >> 2;
        if (full > 0) {
            int srcn = __shfl(idx, g, 64);
            uint4 v = hb[srcn * 16 + c];
            for (int j = 1; j < full; ++j) {
                int srcn2 = __shfl(idx, j * 4 + g, 64);
                uint4 v2 = hb[srcn2 * 16 + c];
                float f[8];
                unpack8(v, f);
#pragma unroll
                for (int k = 0; k < 8; ++k) acc[k] += f[k];
                v = v2;
            }
            float f[8];
            unpack8(v, f);
#pragma unroll
            for (int k = 0; k < 8; ++k) acc[k] += f[k];
        }
        int q = full * 4 + g;
        int srcn = __shfl(idx, q, 64);
        if (q < cnt) {
            uint4 v = hb[srcn * 16 + c];
            float f[8];
            unpack8(v, f);
#pragma unroll
            for (int k = 0; k < 8; ++k) acc[k] += f[k];
        }
    }
#pragma unroll
    for (int k = 0; k < 8; ++k) {
        acc[k] += __shfl_xor(acc[k], 16, 64);
        acc[k] += __shfl_xor(acc[k], 32, 64);
    }
    if (lane < 16) {
        uint4 r;
        r.x = ((unsigned)f2bf(acc[1]) << 16) | (unsigned)f2bf(acc[0]);
        r.y = ((unsigned)f2bf(acc[3]) << 16) | (unsigned)f2bf(acc[2]);
        r.z = ((unsigned)f2bf(acc[5]) << 16) | (unsigned)f2bf(acc[4]);
        r.w = ((unsigned)f2bf(acc[7]) << 16) | (unsigned)f2bf(acc[6]);
        ((uint4*)(agg + (size_t)wid * DD))[c] = r;
    }
}

// ---------------- MFMA: h_new = relu([agg,h] @ Bt + bias) -> bf16 (256 rows/block) ----------------
__global__ __launch_bounds__(256) void k_mp_mfma(const unsigned short* __restrict__ Xa,
                                                 const unsigned short* __restrict__ Xh,
                                                 const unsigned short* __restrict__ Bt,
                                                 const float* __restrict__ bias,
                                                 unsigned short* __restrict__ Out) {
    __shared__ unsigned short sB[128 * 256];
    {
        const uint4* s4 = (const uint4*)Bt;
        uint4* d4 = (uint4*)sB;
        for (int i = threadIdx.x; i < 4096; i += 256) d4[i] = s4[i];
    }
    __syncthreads();
    int wave = threadIdx.x >> 6, lane = threadIdx.x & 63;
    int row0 = blockIdx.x * 256 + wave * 64;
    int arow = lane & 15, kgrp = lane >> 4;
    f32x4 acc[4][8];
#pragma unroll
    for (int s = 0; s < 4; ++s)
#pragma unroll
        for (int c = 0; c < 8; ++c) acc[s][c] = (f32x4){0.f, 0.f, 0.f, 0.f};
    const unsigned short* aptr[4];
    const unsigned short* hptr[4];
#pragma unroll
    for (int s = 0; s < 4; ++s) {
        int r = row0 + s * 16 + arow;
        int rr = (r < MROWS) ? r : (MROWS - 1);
        aptr[s] = Xa + (size_t)rr * DD + kgrp * 8;
        hptr[s] = Xh + (size_t)rr * DD + kgrp * 8;
    }
#pragma unroll
    for (int ks = 0; ks < 8; ++ks) {
        short8 a[4];
#pragma unroll
        for (int s = 0; s < 4; ++s)
            a[s] = (ks < 4) ? *(const short8*)(aptr[s] + ks * 32)
                            : *(const short8*)(hptr[s] + (ks - 4) * 32);
#pragma unroll
        for (int c = 0; c < 8; ++c) {
            int n = c * 16 + arow;
            int mst = (ks * 4 + kgrp) ^ (n & 7);
            short8 bfr = *(const short8*)(sB + n * 256 + mst * 8);
#pragma unroll
            for (int s = 0; s < 4; ++s)
                acc[s][c] = __builtin_amdgcn_mfma_f32_16x16x32_bf16(a[s], bfr, acc[s][c], 0, 0, 0);
        }
    }
    float bcol[8];
#pragma unroll
    for (int c = 0; c < 8; ++c) bcol[c] = bias[c * 16 + arow];
#pragma unroll
    for (int s = 0; s < 4; ++s) {
#pragma unroll
        for (int j = 0; j < 4; ++j) {
            int r = row0 + s * 16 + kgrp * 4 + j;
            if (r < MROWS) {
                unsigned short* orow = Out + (size_t)r * DD;
#pragma unroll
                for (int c = 0; c < 8; ++c) {
                    float v = fmaxf(acc[s][c][j] + bcol[c], 0.f);
                    orow[c * 16 + arow] = f2bf(v);
                }
            }
        }
    }
}

// ---------------- MFMA pair+dot: logits + fused batch-max (256 rows/block) ----------------
__global__ __launch_bounds__(256) void k_pair_mfma(const unsigned short* __restrict__ Xh,
                                                   const unsigned short* __restrict__ Abf,
                                                   const unsigned short* __restrict__ Bt,
                                                   const float* __restrict__ bp,
                                                   const float* __restrict__ wout,
                                                   const int* __restrict__ mc,
                                                   float* __restrict__ logits,
                                                   unsigned* __restrict__ mtrans) {
    __shared__ unsigned short sB[128 * 256];
    __shared__ unsigned smax[NB];
    {
        const uint4* s4 = (const uint4*)Bt;
        uint4* d4 = (uint4*)sB;
        for (int i = threadIdx.x; i < 4096; i += 256) d4[i] = s4[i];
        if (threadIdx.x < NB) smax[threadIdx.x] = 0u;
    }
    __syncthreads();
    int wave = threadIdx.x >> 6, lane = threadIdx.x & 63;
    int row0 = blockIdx.x * 256 + wave * 64;
    int arow = lane & 15, kgrp = lane >> 4;
    f32x4 acc[4][8];
#pragma unroll
    for (int s = 0; s < 4; ++s)
#pragma unroll
        for (int c = 0; c < 8; ++c) acc[s][c] = (f32x4){0.f, 0.f, 0.f, 0.f};
    const unsigned short* hptr[4];
    const unsigned short* aptr[4];
#pragma unroll
    for (int s = 0; s < 4; ++s) {
        int r = row0 + s * 16 + arow;
        int rr = (r < MROWS) ? r : (MROWS - 1);
        hptr[s] = Xh + (size_t)rr * DD + kgrp * 8;
        aptr[s] = Abf + (size_t)(rr / NND) * DD + kgrp * 8;
    }
#pragma unroll
    for (int ks = 0; ks < 8; ++ks) {
        short8 a[4];
#pragma unroll
        for (int s = 0; s < 4; ++s)
            a[s] = (ks < 4) ? *(const short8*)(hptr[s] + ks * 32)
                            : *(const short8*)(aptr[s] + (ks - 4) * 32);
#pragma unroll
        for (int c = 0; c < 8; ++c) {
            int n = c * 16 + arow;
            int mst = (ks * 4 + kgrp) ^ (n & 7);
            short8 bfr = *(const short8*)(sB + n * 256 + mst * 8);
#pragma unroll
            for (int s = 0; s < 4; ++s)
                acc[s][c] = __builtin_amdgcn_mfma_f32_16x16x32_bf16(a[s], bfr, acc[s][c], 0, 0, 0);
        }
    }
    float bpc[8], wc[8];
#pragma unroll
    for (int c = 0; c < 8; ++c) {
        int col = c * 16 + arow;
        bpc[c] = bp[col];
        wc[c] = wout[col];
    }
#pragma unroll
    for (int s = 0; s < 4; ++s) {
#pragma unroll
        for (int j = 0; j < 4; ++j) {
            float v = 0.f;
#pragma unroll
            for (int c = 0; c < 8; ++c)
                v += fmaxf(acc[s][c][j] + bpc[c], 0.f) * wc[c];
            v += __shfl_xor(v, 1, 64);
            v += __shfl_xor(v, 2, 64);
            v += __shfl_xor(v, 4, 64);
            v += __shfl_xor(v, 8, 64);
            int r = row0 + s * 16 + kgrp * 4 + j;
            if (arow == 0 && r < MROWS) {
                float lv = mc[r] ? v : NEGINF;
                logits[r] = lv;
                atomicMax(&smax[r / NND], ftrans(lv));
            }
        }
    }
    __syncthreads();
    if (threadIdx.x < NB && smax[threadIdx.x] != 0u)
        atomicMax(mtrans + threadIdx.x, smax[threadIdx.x]);
}

// ---------------- fused sumexp + context ----------------
#define CTX_CH 128
#define CTX_RPB ((NND + CTX_CH - 1) / CTX_CH)
__global__ __launch_bounds__(256) void k_ctxsum(const float* __restrict__ logits, const unsigned short* __restrict__ h,
                                                const unsigned* __restrict__ mtrans, float* S, float* ctx) {
    int b = blockIdx.x >> 7, chunk = blockIdx.x & (CTX_CH - 1);
    int rowstart = chunk * CTX_RPB;
    int rowend = min(rowstart + CTX_RPB, NND);
    int wave = threadIdx.x >> 6, lane = threadIdx.x & 63;
    int g = lane >> 4, c = lane & 15;
    float m = finv(mtrans[b]);
    float acc[8] = {0.f,0.f,0.f,0.f,0.f,0.f,0.f,0.f};
    float ws = 0.f;
    const uint4* hb = (const uint4*)(h + (size_t)b * NND * DD);
    const float* lg = logits + b * NND;
    for (int r0 = rowstart + wave * 4; r0 < rowend; r0 += 16) {
        int row = r0 + g;
        if (row < rowend) {
            float w = expf(lg[row] - m);
            ws += w;
            uint4 v = hb[row * 16 + c];
            float f[8];
            unpack8(v, f);
#pragma unroll
            for (int k = 0; k < 8; ++k) acc[k] += w * f[k];
        }
    }
#pragma unroll
    for (int k = 0; k < 8; ++k) {
        acc[k] += __shfl_xor(acc[k], 16, 64);
        acc[k] += __shfl_xor(acc[k], 32, 64);
    }
    ws += __shfl_xor(ws, 16, 64);
    ws += __shfl_xor(ws, 32, 64);
    __shared__ float sctx[4][128];
    __shared__ float sws[4];
    if (lane < 16) {
#pragma unroll
        for (int k = 0; k < 8; ++k) sctx[wave][lane * 8 + k] = acc[k];
    }
    if (lane == 0) sws[wave] = ws;
    __syncthreads();
    int tid = threadIdx.x;
    if (tid < 128) {
        float t = sctx[0][tid] + sctx[1][tid] + sctx[2][tid] + sctx[3][tid];
        atomicAdd(ctx + b * DD + tid, t);
    }
    if (tid == 0) atomicAdd(S + b, sws[0] + sws[1] + sws[2] + sws[3]);
}

// ---------------- log_probs out + value head (block 313) ----------------
__global__ __launch_bounds__(256) void k_final(const float* __restrict__ logits, const unsigned* __restrict__ mtrans,
                                               const float* __restrict__ S, const float* __restrict__ ctx,
                                               const float* __restrict__ av, const float* __restrict__ Wv,
                                               const float* __restrict__ bv, const float* __restrict__ wvo,
                                               float* __restrict__ out) {
    int tid = threadIdx.x;
    if (blockIdx.x == 313) {
        __shared__ float red[512];
#pragma unroll
        for (int half = 0; half < 2; ++half) {
            for (int t = tid; t < 2 * 256; t += 256) {
                int b = half * 2 + (t >> 7), j = t & 127;
                float sb = S[b];
                float s1 = 0.f, s2 = 0.f;
                for (int k = 0; k < 128; ++k) s1 += ctx[b * DD + k] * Wv[k * DD + j];
                for (int k = 0; k < 128; ++k) s2 += av[b * DD + k] * Wv[(128 + k) * DD + j];
                float acc = bv[j] + s1 / sb + s2;
                red[t] = fmaxf(acc, 0.f) * wvo[j];
            }
            __syncthreads();
            int j = tid & 127;
            for (int off = 64; off; off >>= 1) {
                if (j < off) {
                    red[tid] += red[tid + off];
                    red[tid + 256] += red[tid + 256 + off];
                }
                __syncthreads();
            }
            if (tid < 2) out[NB * NND + half * 2 + tid] = red[tid * 128];
            __syncthreads();
        }
        return;
    }
    int g = blockIdx.x * 256 + tid;
    if (g >= NB * NND) return;
    int b = g / NND;
    out[g] = logits[g] - finv(mtrans[b]) - logf(S[b]);
}

extern "C" void kernel_launch(void* const* d_in, const int* in_sizes, int n_in,
                              void* d_out, int out_size, void* d_ws, size_t ws_size,
                              hipStream_t stream) {
    const float* nodes = (const float*)d_in[0];
    const int* links = (const int*)d_in[1];
    const void* mask = d_in[2];
    const float* ad = (const float*)d_in[3];
    const float* Win = (const float*)d_in[4];
    const float* bin = (const float*)d_in[5];
    const float* Wm1 = (const float*)d_in[6];
    const float* Ws1 = (const float*)d_in[7];
    const float* b1 = (const float*)d_in[8];
    const float* Wm2 = (const float*)d_in[9];
    const float* Ws2 = (const float*)d_in[10];
    const float* b2 = (const float*)d_in[11];
    const float* Wad = (const float*)d_in[12];
    const float* bad = (const float*)d_in[13];
    const float* Wp = (const float*)d_in[14];
    const float* bp = (const float*)d_in[15];
    const float* wout = (const float*)d_in[16];
    const float* Wv = (const float*)d_in[17];
    const float* bv = (const float*)d_in[18];
    const float* wvo = (const float*)d_in[19];
    float* out = (float*)d_out;

    unsigned short* hA = (unsigned short*)d_ws;     // h0/h1/h2
    unsigned short* hB = hA + 10240000;             // agg
    unsigned short* B1t = hB + 10240000;
    unsigned short* B2t = B1t + 32768;
    unsigned short* Bpt = B2t + 32768;
    unsigned short* a_bf = Bpt + 32768;
    float* logits = (float*)(a_bf + 512);
    float* a_vec = logits + 80000;
    float* Sexp = a_vec + 512;
    float* ctxb = Sexp + 64;
    unsigned* mtrans = (unsigned*)(ctxb + 512);
    int* dp = (int*)(mtrans + 64);                  // NB*NCH*NND = 2,560,000
    int* offs = dp + NB * NCH * NND;                // 80,064
    int* csr = offs + 80064;                        // 1,280,000
    int* mc = csr + 1280000;                        // 80,000
    int* flag = mc + 80000;                         // 64
    int* segsum = flag + 64;                        // 128
    float* pstats = (float*)(segsum + 128);         // STATB*16 = 4096

    k_init<<<3 + STATB, 256, 0, stream>>>(mtrans, Sexp, ctxb, (const unsigned char*)mask, flag, nodes, pstats);
    k_setup<<<DEGB + H0B + 313 + 3 + 1, 256, 0, stream>>>(links, dp, nodes, pstats, Win, bin, hA,
                                                          mask, flag, mc,
                                                          Wm1, Ws1, Wm2, Ws2, Wp, B1t, B2t, Bpt,
                                                          ad, Wad, bad, a_vec, a_bf);
    k_scanA<<<NB * NSEG, 1024, 0, stream>>>(dp, offs, segsum);
    k_scanC<<<NB * NSEG, 1024, 0, stream>>>(dp, offs, segsum);
    k_fill<<<DEGB, 256, 0, stream>>>(links, dp, csr);

    k_gather<<<20000, 256, 0, stream>>>(hA, offs, csr, hB);
    k_mp_mfma<<<313, 256, 0, stream>>>(hB, hA, B1t, b1, hA);
    k_gather<<<20000, 256, 0, stream>>>(hA, offs, csr, hB);
    k_mp_mfma<<<313, 256, 0, stream>>>(hB, hA, B2t, b2, hA);

    k_pair_mfma<<<313, 256, 0, stream>>>(hA, a_bf, Bpt, bp, wout, mc, logits, mtrans);
    k_ctxsum<<<NB * CTX_CH, 256, 0, stream>>>(logits, hA, mtrans, Sexp, ctxb);
    k_final<<<314, 256, 0, stream>>>(logits, mtrans, Sexp, ctxb, a_vec, Wv, bv, wvo, out);
}